// Round 7
// baseline (1003.775 us; speedup 1.0000x reference)
//
#include <hip/hip_runtime.h>
#include <math.h>

// GAT: 3 hidden GATConv layers (H=4, D=64, HID=256) + LN + leaky + residual,
// then output GATConv (H=1, C=40). N=100000 nodes, E=1600000 edges.
//
// Round 16: zero-LDS direct-global MFMA GEMMs. R15 exposed the persistent
// GEMM at 80 us: 152KB LDS -> 1 block/CU, barrier/K-iter, MLP ~0, 1.3 TB/s.
// B (128KB) and per-step A-tile (8KB) are L1/L2-resident, so fragments are
// read DIRECTLY from global (same values the LDS path staged): no LDS, no
// barriers, VGPR-limited occupancy (~12 waves/CU), compiler pipelines loads
// across K. 128x128 tile / 4 waves / grid x2 col-blocks. gemm_out same.
// Fused el/er epilogue kept. CSR build + aggregates unchanged from R15.

#define NEG_SLOPE 0.2f

typedef __attribute__((ext_vector_type(8))) short bf16x8;
typedef __attribute__((ext_vector_type(4))) float floatx4;

__device__ __forceinline__ float leaky(float x) { return x >= 0.f ? x : NEG_SLOPE * x; }

__device__ __forceinline__ unsigned short f2bf(float f) {
    unsigned u = __builtin_bit_cast(unsigned, f);
    u += 0x7fffu + ((u >> 16) & 1u);  // RNE
    return (unsigned short)(u >> 16);
}
__device__ __forceinline__ float bf2f(unsigned short h) {
    unsigned u = ((unsigned)h) << 16;
    return __builtin_bit_cast(float, u);
}

// ---------------- bucketed CSR build ----------------
__global__ __launch_bounds__(256) void bucket_count(const int* __restrict__ dst,
                                                    int* __restrict__ bcnt, int E, int nbkt) {
    __shared__ int h[1024];
    for (int i = threadIdx.x; i < nbkt; i += 256) h[i] = 0;
    __syncthreads();
    const int base = blockIdx.x * 8192;
#pragma unroll 4
    for (int i = 0; i < 32; ++i) {
        int e = base + threadIdx.x + i * 256;
        if (e < E) atomicAdd(&h[dst[e] >> 7], 1);
    }
    __syncthreads();
    for (int i = threadIdx.x; i < nbkt; i += 256) {
        int v = h[i];
        if (v) atomicAdd(&bcnt[i], v);
    }
}

__global__ __launch_bounds__(256) void bucket_scan(const int* __restrict__ bcnt,
                                                   int* __restrict__ bbase,
                                                   int* __restrict__ bcursor, int nbkt) {
    __shared__ int s[256];
    const int t = threadIdx.x;
    int c[4];
    int tsum = 0;
#pragma unroll
    for (int j = 0; j < 4; ++j) {
        int i = t * 4 + j;
        c[j] = (i < nbkt) ? bcnt[i] : 0;
        tsum += c[j];
    }
    s[t] = tsum;
    __syncthreads();
    for (int off = 1; off < 256; off <<= 1) {
        int v = (t >= off) ? s[t - off] : 0;
        __syncthreads();
        s[t] += v;
        __syncthreads();
    }
    int excl = s[t] - tsum;
#pragma unroll
    for (int j = 0; j < 4; ++j) {
        int i = t * 4 + j;
        if (i < nbkt) {
            bbase[i] = excl;
            bcursor[i] = excl;
        }
        excl += c[j];
    }
}

__global__ __launch_bounds__(256) void bucket_partition(const int* __restrict__ src,
                                                        const int* __restrict__ dst,
                                                        int* __restrict__ bcursor,
                                                        int2* __restrict__ pairs, int E, int nbkt) {
    __shared__ int h[1024];
    __shared__ int basech[1024];
    for (int i = threadIdx.x; i < nbkt; i += 256) h[i] = 0;
    __syncthreads();
    const int base = blockIdx.x * 8192;
#pragma unroll 4
    for (int i = 0; i < 32; ++i) {
        int e = base + threadIdx.x + i * 256;
        if (e < E) atomicAdd(&h[dst[e] >> 7], 1);
    }
    __syncthreads();
    for (int i = threadIdx.x; i < nbkt; i += 256) {
        int v = h[i];
        basech[i] = v ? atomicAdd(&bcursor[i], v) : 0;
    }
    __syncthreads();
    for (int i = threadIdx.x; i < nbkt; i += 256) h[i] = 0;
    __syncthreads();
#pragma unroll 4
    for (int i = 0; i < 32; ++i) {
        int e = base + threadIdx.x + i * 256;
        if (e < E) {
            int d = dst[e], b = d >> 7;
            int r = atomicAdd(&h[b], 1);
            pairs[basech[b] + r] = make_int2(src[e], d);
        }
    }
}

__global__ __launch_bounds__(256) void csr_bucket(const int2* __restrict__ pairs,
                                                  const int* __restrict__ bbase,
                                                  int* __restrict__ start, int* __restrict__ endp,
                                                  int* __restrict__ col, int N, int E, int nbkt) {
    const int b = blockIdx.x;
    const int node0 = b << 7;
    int nc = N - node0;
    if (nc <= 0) return;
    if (nc > 128) nc = 128;
    __shared__ int cnt[128];
    __shared__ int s[128];
    const int t = threadIdx.x;
    if (t < 128) cnt[t] = 0;
    __syncthreads();
    const int ebase = bbase[b];
    const int eend = (b + 1 < nbkt) ? bbase[b + 1] : E;
    for (int e = ebase + t; e < eend; e += 256) {
        atomicAdd(&cnt[pairs[e].y - node0], 1);
    }
    __syncthreads();
    if (t < 128) s[t] = cnt[t];
    __syncthreads();
    for (int off = 1; off < 128; off <<= 1) {
        int v = 0;
        if (t < 128 && t >= off) v = s[t - off];
        __syncthreads();
        if (t < 128) s[t] += v;
        __syncthreads();
    }
    if (t < nc) {
        start[node0 + t] = ebase + s[t] - cnt[t];
        endp[node0 + t] = ebase + s[t];
    }
    if (t < 128) cnt[t] = s[t] - cnt[t];  // -> exclusive cursor
    __syncthreads();
    for (int e = ebase + t; e < eend; e += 256) {
        int2 pr = pairs[e];
        int r = atomicAdd(&cnt[pr.y - node0], 1);
        col[ebase + r] = pr.x;
    }
}

// ---------------- weight pre-transpose: Wt[l][n][k] = bf16(W[l][k][n]) ----------------
__global__ void transpose_w(const float* __restrict__ W, unsigned short* __restrict__ Wt) {
    int idx = blockIdx.x * 256 + threadIdx.x;
    int l = idx >> 16, r = idx & 65535;
    int k = r >> 8, n = r & 255;
    Wt[l * 65536 + n * 256 + k] = f2bf(W[l * 65536 + k * 256 + n]);
}

__global__ void transpose_wo(const float* __restrict__ W, unsigned short* __restrict__ Wt) {
    int idx = blockIdx.x * 256 + threadIdx.x;
    int n = idx >> 8, k = idx & 255;
    Wt[n * 256 + k] = (n < 40) ? f2bf(W[k * 40 + n]) : (unsigned short)0;
}

// ---------------- zero-LDS direct-global MFMA GEMM + fused scores ----------------
// Block: 256 thr / 4 waves, tile 128 rows x 128 cols (grid x2 col-blocks).
// Fragments read directly from global (L1/L2-resident); no LDS, no barriers.
template <bool F32>
__global__ __launch_bounds__(256) void gemm_fused(
    const void* __restrict__ Av, const unsigned short* __restrict__ Wt,
    const float* __restrict__ al, const float* __restrict__ ar,
    unsigned short* __restrict__ Cb, float* __restrict__ el, float* __restrict__ er, int M) {
    const unsigned short* Ab = (const unsigned short*)Av;
    const float* Af = (const float*)Av;
    const int tid = threadIdx.x;
    const int lane = tid & 63, wid = tid >> 6;
    const int bx = blockIdx.x & 1;
    const int by = blockIdx.x >> 1;
    const int row0 = by * 128, col0 = bx * 128;
    const int wm = (wid >> 1) * 64;   // 0 or 64
    const int wn = (wid & 1) * 64;    // 0 or 64
    const int q = lane >> 4, m = lane & 15;

    // per-fragment base pointers (kb folds into load immediate offset)
    const unsigned short* ap[4];
    const float* apf[4];
    const unsigned short* bp[4];
#pragma unroll
    for (int i = 0; i < 4; ++i) {
        int r = row0 + wm + i * 16 + m;
        if (r >= M) r = M - 1;
        ap[i] = Ab + (size_t)r * 256 + q * 8;
        apf[i] = Af + (size_t)r * 256 + q * 8;
        bp[i] = Wt + (size_t)(col0 + wn + i * 16 + m) * 256 + q * 8;
    }

    floatx4 acc[4][4] = {};
#pragma unroll 2
    for (int kb = 0; kb < 256; kb += 32) {
        bf16x8 af[4], bfr[4];
#pragma unroll
        for (int i = 0; i < 4; ++i) bfr[i] = *(const bf16x8*)(bp[i] + kb);
#pragma unroll
        for (int i = 0; i < 4; ++i) {
            if constexpr (F32) {
                const float* p = apf[i] + kb;
                float4 f0 = *(const float4*)p;
                float4 f1 = *(const float4*)(p + 4);
                bf16x8 v;
                v[0] = (short)f2bf(f0.x); v[1] = (short)f2bf(f0.y);
                v[2] = (short)f2bf(f0.z); v[3] = (short)f2bf(f0.w);
                v[4] = (short)f2bf(f1.x); v[5] = (short)f2bf(f1.y);
                v[6] = (short)f2bf(f1.z); v[7] = (short)f2bf(f1.w);
                af[i] = v;
            } else {
                af[i] = *(const bf16x8*)(ap[i] + kb);
            }
        }
#pragma unroll
        for (int i = 0; i < 4; ++i)
#pragma unroll
            for (int j = 0; j < 4; ++j)
                acc[i][j] = __builtin_amdgcn_mfma_f32_16x16x32_bf16(af[i], bfr[j], acc[i][j], 0, 0, 0);
    }

    // epilogue: C store (layout col=lane&15, row=q*4+reg) + fused head dots
    const int c = lane & 15;
#pragma unroll
    for (int i = 0; i < 4; ++i)
#pragma unroll
        for (int j = 0; j < 4; ++j)
#pragma unroll
            for (int r = 0; r < 4; ++r) {
                int grow = row0 + wm + i * 16 + q * 4 + r;
                int gcol = col0 + wn + j * 16 + c;
                if (grow < M) Cb[(size_t)grow * 256 + gcol] = f2bf(acc[i][j][r]);
            }

    const int head = bx * 2 + (wn >> 6);
    const float* alh = al + head * 64;
    const float* arh = ar + head * 64;
    float a0 = alh[c], a1 = alh[16 + c], a2 = alh[32 + c], a3 = alh[48 + c];
    float r0 = arh[c], r1 = arh[16 + c], r2 = arh[32 + c], r3 = arh[48 + c];
#pragma unroll
    for (int i = 0; i < 4; ++i)
#pragma unroll
        for (int r = 0; r < 4; ++r) {
            float pel = acc[i][0][r] * a0 + acc[i][1][r] * a1 + acc[i][2][r] * a2 + acc[i][3][r] * a3;
            float per = acc[i][0][r] * r0 + acc[i][1][r] * r1 + acc[i][2][r] * r2 + acc[i][3][r] * r3;
#pragma unroll
            for (int off = 8; off >= 1; off >>= 1) {
                pel += __shfl_xor(pel, off);
                per += __shfl_xor(per, off);
            }
            if (c == 0) {
                int grow = row0 + wm + i * 16 + q * 4 + r;
                if (grow < M) {
                    el[(size_t)grow * 4 + head] = pel;
                    er[(size_t)grow * 4 + head] = per;
                }
            }
        }
}

// ---------------- output GEMM: feat_o[N,64pad] = h_bf[N,256] @ W_o, zero-LDS ----------------
#define OSTR 64   // feat_o row stride (elements): 128B line-aligned
__global__ __launch_bounds__(256) void gemm_out_mfma(const unsigned short* __restrict__ h,
                                                     const unsigned short* __restrict__ Wt,
                                                     const float* __restrict__ alo,
                                                     const float* __restrict__ aro,
                                                     unsigned short* __restrict__ feat_o,
                                                     float* __restrict__ elo,
                                                     float* __restrict__ ero, int N) {
    const int tid = threadIdx.x;
    const int row0 = blockIdx.x * 128;
    const int lane = tid & 63, wid = tid >> 6;
    const int q = lane >> 4, m = lane & 15;

    const unsigned short* ap[2];
    const unsigned short* bp[3];
#pragma unroll
    for (int i = 0; i < 2; ++i) {
        int r = row0 + wid * 32 + i * 16 + m;
        if (r >= N) r = N - 1;
        ap[i] = h + (size_t)r * 256 + q * 8;
    }
#pragma unroll
    for (int j = 0; j < 3; ++j) bp[j] = Wt + (size_t)(j * 16 + m) * 256 + q * 8;

    floatx4 acc[2][3] = {};
#pragma unroll 2
    for (int kb = 0; kb < 256; kb += 32) {
        bf16x8 af[2], bfr[3];
#pragma unroll
        for (int i = 0; i < 2; ++i) af[i] = *(const bf16x8*)(ap[i] + kb);
#pragma unroll
        for (int j = 0; j < 3; ++j) bfr[j] = *(const bf16x8*)(bp[j] + kb);
#pragma unroll
        for (int i = 0; i < 2; ++i)
#pragma unroll
            for (int j = 0; j < 3; ++j)
                acc[i][j] = __builtin_amdgcn_mfma_f32_16x16x32_bf16(af[i], bfr[j], acc[i][j], 0, 0, 0);
    }

    const int c = lane & 15;
#pragma unroll
    for (int i = 0; i < 2; ++i)
#pragma unroll
        for (int j = 0; j < 3; ++j)
#pragma unroll
            for (int r = 0; r < 4; ++r) {
                int grow = row0 + wid * 32 + i * 16 + q * 4 + r;
                int gcol = j * 16 + c;
                if (grow < N && gcol < 40) feat_o[(size_t)grow * OSTR + gcol] = f2bf(acc[i][j][r]);
            }

    float aj[3], rj[3];
#pragma unroll
    for (int j = 0; j < 3; ++j) {
        int gcol = j * 16 + c;
        aj[j] = gcol < 40 ? alo[gcol] : 0.f;
        rj[j] = gcol < 40 ? aro[gcol] : 0.f;
    }
#pragma unroll
    for (int i = 0; i < 2; ++i)
#pragma unroll
        for (int r = 0; r < 4; ++r) {
            float pl = acc[i][0][r] * aj[0] + acc[i][1][r] * aj[1] + acc[i][2][r] * aj[2];
            float pr = acc[i][0][r] * rj[0] + acc[i][1][r] * rj[1] + acc[i][2][r] * rj[2];
#pragma unroll
            for (int off = 8; off >= 1; off >>= 1) {
                pl += __shfl_xor(pl, off);
                pr += __shfl_xor(pr, off);
            }
            if (c == 0) {
                int grow = row0 + wid * 32 + i * 16 + q * 4 + r;
                if (grow < N) {
                    elo[grow] = pl;
                    ero[grow] = pr;
                }
            }
        }
}

// ---------------- hidden-layer aggregation: single pass + fused epilogue ----------------
__global__ __launch_bounds__(256) void aggregate_hidden(
    const unsigned short* __restrict__ feat, const float* __restrict__ el,
    const float* __restrict__ er, const int* __restrict__ start, const int* __restrict__ endp,
    const int* __restrict__ col, const float* __restrict__ bias, const float* __restrict__ lng,
    const float* __restrict__ lnb, const unsigned short* __restrict__ h_in,
    const float* __restrict__ h_in_f32,
    unsigned short* __restrict__ h_out, int node0, int nend) {
    int node = node0 + blockIdx.x * 4 + (threadIdx.x >> 6);
    int lane = threadIdx.x & 63;
    if (node >= nend) return;
    int begin = __builtin_amdgcn_readfirstlane(start[node]);
    int end = __builtin_amdgcn_readfirstlane(endp[node]);
    const int head = lane >> 4;
    const float erh = er[(size_t)node * 4 + head];

    const int ch = lane * 4;
    const unsigned short* fbase = feat + ch;
    const size_t hstr = 256;
    float4 acc = {0.f, 0.f, 0.f, 0.f};
    float ssum = 0.f;
    int e = begin;
    for (; e + 7 < end; e += 8) {
        int sA = col[e], sB = col[e + 1], sC = col[e + 2], sD = col[e + 3];
        int sE = col[e + 4], sF = col[e + 5], sG = col[e + 6], sH = col[e + 7];
        float eA = el[(size_t)sA * 4 + head];
        float eB = el[(size_t)sB * 4 + head];
        float eC = el[(size_t)sC * 4 + head];
        float eD = el[(size_t)sD * 4 + head];
        float eE = el[(size_t)sE * 4 + head];
        float eF = el[(size_t)sF * 4 + head];
        float eG = el[(size_t)sG * 4 + head];
        float eH = el[(size_t)sH * 4 + head];
        ushort4 uA = *(const ushort4*)(fbase + sA * hstr);
        ushort4 uB = *(const ushort4*)(fbase + sB * hstr);
        ushort4 uC = *(const ushort4*)(fbase + sC * hstr);
        ushort4 uD = *(const ushort4*)(fbase + sD * hstr);
        ushort4 uE = *(const ushort4*)(fbase + sE * hstr);
        ushort4 uF = *(const ushort4*)(fbase + sF * hstr);
        ushort4 uG = *(const ushort4*)(fbase + sG * hstr);
        ushort4 uH = *(const ushort4*)(fbase + sH * hstr);
        float wA = __expf(leaky(eA + erh));
        float wB = __expf(leaky(eB + erh));
        float wC = __expf(leaky(eC + erh));
        float wD = __expf(leaky(eD + erh));
        float wE = __expf(leaky(eE + erh));
        float wF = __expf(leaky(eF + erh));
        float wG = __expf(leaky(eG + erh));
        float wH = __expf(leaky(eH + erh));
        ssum += wA + wB + wC + wD + wE + wF + wG + wH;
        acc.x = fmaf(wA, bf2f(uA.x), acc.x); acc.y = fmaf(wA, bf2f(uA.y), acc.y);
        acc.z = fmaf(wA, bf2f(uA.z), acc.z); acc.w = fmaf(wA, bf2f(uA.w), acc.w);
        acc.x = fmaf(wB, bf2f(uB.x), acc.x); acc.y = fmaf(wB, bf2f(uB.y), acc.y);
        acc.z = fmaf(wB, bf2f(uB.z), acc.z); acc.w = fmaf(wB, bf2f(uB.w), acc.w);
        acc.x = fmaf(wC, bf2f(uC.x), acc.x); acc.y = fmaf(wC, bf2f(uC.y), acc.y);
        acc.z = fmaf(wC, bf2f(uC.z), acc.z); acc.w = fmaf(wC, bf2f(uC.w), acc.w);
        acc.x = fmaf(wD, bf2f(uD.x), acc.x); acc.y = fmaf(wD, bf2f(uD.y), acc.y);
        acc.z = fmaf(wD, bf2f(uD.z), acc.z); acc.w = fmaf(wD, bf2f(uD.w), acc.w);
        acc.x = fmaf(wE, bf2f(uE.x), acc.x); acc.y = fmaf(wE, bf2f(uE.y), acc.y);
        acc.z = fmaf(wE, bf2f(uE.z), acc.z); acc.w = fmaf(wE, bf2f(uE.w), acc.w);
        acc.x = fmaf(wF, bf2f(uF.x), acc.x); acc.y = fmaf(wF, bf2f(uF.y), acc.y);
        acc.z = fmaf(wF, bf2f(uF.z), acc.z); acc.w = fmaf(wF, bf2f(uF.w), acc.w);
        acc.x = fmaf(wG, bf2f(uG.x), acc.x); acc.y = fmaf(wG, bf2f(uG.y), acc.y);
        acc.z = fmaf(wG, bf2f(uG.z), acc.z); acc.w = fmaf(wG, bf2f(uG.w), acc.w);
        acc.x = fmaf(wH, bf2f(uH.x), acc.x); acc.y = fmaf(wH, bf2f(uH.y), acc.y);
        acc.z = fmaf(wH, bf2f(uH.z), acc.z); acc.w = fmaf(wH, bf2f(uH.w), acc.w);
    }
    for (; e < end; ++e) {
        int sA = col[e];
        float wA = __expf(leaky(el[(size_t)sA * 4 + head] + erh));
        ushort4 uA = *(const ushort4*)(fbase + sA * hstr);
        ssum += wA;
        acc.x = fmaf(wA, bf2f(uA.x), acc.x); acc.y = fmaf(wA, bf2f(uA.y), acc.y);
        acc.z = fmaf(wA, bf2f(uA.z), acc.z); acc.w = fmaf(wA, bf2f(uA.w), acc.w);
    }
    float inv = ssum > 0.f ? 1.f / ssum : 0.f;
    acc.x *= inv; acc.y *= inv; acc.z *= inv; acc.w *= inv;

    float4 bb = *(const float4*)(bias + ch);
    float x0 = acc.x + bb.x, x1 = acc.y + bb.y, x2 = acc.z + bb.z, x3 = acc.w + bb.w;
    x0 = x0 > 0.f ? x0 : expm1f(x0);
    x1 = x1 > 0.f ? x1 : expm1f(x1);
    x2 = x2 > 0.f ? x2 : expm1f(x2);
    x3 = x3 > 0.f ? x3 : expm1f(x3);
    float lsum = x0 + x1 + x2 + x3;
    float lsq = x0 * x0 + x1 * x1 + x2 * x2 + x3 * x3;
#pragma unroll
    for (int off = 32; off >= 1; off >>= 1) {
        lsum += __shfl_xor(lsum, off);
        lsq += __shfl_xor(lsq, off);
    }
    float mu = lsum * (1.f / 256.f);
    float var = lsq * (1.f / 256.f) - mu * mu;
    float rstd = rsqrtf(var + 1e-5f);
    float4 g4 = *(const float4*)(lng + ch);
    float4 b4 = *(const float4*)(lnb + ch);
    float rx, ry, rz, rw;
    if (h_in_f32) {
        float4 hf = *(const float4*)(h_in_f32 + (size_t)node * 256 + ch);
        rx = hf.x; ry = hf.y; rz = hf.z; rw = hf.w;
    } else {
        ushort4 hi = *(const ushort4*)(h_in + (size_t)node * 256 + ch);
        rx = bf2f(hi.x); ry = bf2f(hi.y); rz = bf2f(hi.z); rw = bf2f(hi.w);
    }
    float y0 = (x0 - mu) * rstd * g4.x + b4.x;
    float y1 = (x1 - mu) * rstd * g4.y + b4.y;
    float y2 = (x2 - mu) * rstd * g4.z + b4.z;
    float y3 = (x3 - mu) * rstd * g4.w + b4.w;
    y0 = (y0 >= 0.f ? y0 : 0.2f * y0) + rx;
    y1 = (y1 >= 0.f ? y1 : 0.2f * y1) + ry;
    y2 = (y2 >= 0.f ? y2 : 0.2f * y2) + rz;
    y3 = (y3 >= 0.f ? y3 : 0.2f * y3) + rw;
    ushort4 o;
    o.x = f2bf(y0); o.y = f2bf(y1); o.z = f2bf(y2); o.w = f2bf(y3);
    *(ushort4*)(h_out + (size_t)node * 256 + ch) = o;
}

// ---------------- output aggregation: logits[N,40], single pass ----------------
__global__ __launch_bounds__(256) void aggregate_out(const unsigned short* __restrict__ feat_o,
                                                     const float* __restrict__ elo,
                                                     const float* __restrict__ ero,
                                                     const int* __restrict__ start,
                                                     const int* __restrict__ endp,
                                                     const int* __restrict__ col,
                                                     const float* __restrict__ bias_o,
                                                     float* __restrict__ out, int node0, int nend) {
    int node = node0 + blockIdx.x * 4 + (threadIdx.x >> 6);
    int lane = threadIdx.x & 63;
    if (node >= nend) return;
    int begin = __builtin_amdgcn_readfirstlane(start[node]);
    int end = __builtin_amdgcn_readfirstlane(endp[node]);
    float ern = ero[node];
    int cc = lane < 40 ? lane : 0;
    float acc = 0.f, ssum = 0.f;
    int e = begin;
    for (; e + 7 < end; e += 8) {
        int sA = col[e], sB = col[e + 1], sC = col[e + 2], sD = col[e + 3];
        int sE = col[e + 4], sF = col[e + 5], sG = col[e + 6], sH = col[e + 7];
        float eA = elo[sA], eB = elo[sB], eC = elo[sC], eD = elo[sD];
        float eE = elo[sE], eF = elo[sF], eG = elo[sG], eH = elo[sH];
        unsigned short fA = feat_o[(size_t)sA * OSTR + cc];
        unsigned short fB = feat_o[(size_t)sB * OSTR + cc];
        unsigned short fC = feat_o[(size_t)sC * OSTR + cc];
        unsigned short fD = feat_o[(size_t)sD * OSTR + cc];
        unsigned short fE = feat_o[(size_t)sE * OSTR + cc];
        unsigned short fF = feat_o[(size_t)sF * OSTR + cc];
        unsigned short fG = feat_o[(size_t)sG * OSTR + cc];
        unsigned short fH = feat_o[(size_t)sH * OSTR + cc];
        float wA = __expf(leaky(eA + ern));
        float wB = __expf(leaky(eB + ern));
        float wC = __expf(leaky(eC + ern));
        float wD = __expf(leaky(eD + ern));
        float wE = __expf(leaky(eE + ern));
        float wF = __expf(leaky(eF + ern));
        float wG = __expf(leaky(eG + ern));
        float wH = __expf(leaky(eH + ern));
        ssum += wA + wB + wC + wD + wE + wF + wG + wH;
        acc = fmaf(wA, bf2f(fA), acc);
        acc = fmaf(wB, bf2f(fB), acc);
        acc = fmaf(wC, bf2f(fC), acc);
        acc = fmaf(wD, bf2f(fD), acc);
        acc = fmaf(wE, bf2f(fE), acc);
        acc = fmaf(wF, bf2f(fF), acc);
        acc = fmaf(wG, bf2f(fG), acc);
        acc = fmaf(wH, bf2f(fH), acc);
    }
    for (; e < end; ++e) {
        int sA = col[e];
        float wA = __expf(leaky(elo[sA] + ern));
        ssum += wA;
        acc = fmaf(wA, bf2f(feat_o[(size_t)sA * OSTR + cc]), acc);
    }
    float inv = ssum > 0.f ? 1.f / ssum : 0.f;
    if (lane < 40) out[(size_t)node * 40 + lane] = acc * inv + bias_o[lane];
}

// ---------------- launcher ----------------
extern "C" void kernel_launch(void* const* d_in, const int* in_sizes, int n_in,
                              void* d_out, int out_size, void* d_ws, size_t ws_size,
                              hipStream_t stream) {
    const float* x = (const float*)d_in[0];
    const float* W_h = (const float*)d_in[1];
    const float* al_h = (const float*)d_in[2];
    const float* ar_h = (const float*)d_in[3];
    const float* bias_h = (const float*)d_in[4];
    const float* ln_g = (const float*)d_in[5];
    const float* ln_b = (const float*)d_in[6];
    const float* W_o = (const float*)d_in[7];
    const float* al_o = (const float*)d_in[8];
    const float* ar_o = (const float*)d_in[9];
    const float* bias_o = (const float*)d_in[10];
    const int* esrc = (const int*)d_in[11];
    const int* edst = (const int*)d_in[12];
    const int N = in_sizes[0] / 256;
    const int E = in_sizes[11];
    float* out = (float*)d_out;

    char* ws = (char*)d_ws;
    size_t off = 0;
    auto walloc = [&](size_t bytes) -> void* {
        void* p = ws + off;
        off += (bytes + 255) & ~(size_t)255;
        return p;
    };
    unsigned short* h_bf = (unsigned short*)walloc((size_t)N * 256 * 2);
    unsigned short* feat_bf = (unsigned short*)walloc((size_t)N * 256 * 2);
    unsigned short* Wt = (unsigned short*)walloc((size_t)3 * 65536 * 2);
    unsigned short* Wt_o = (unsigned short*)walloc((size_t)48 * 256 * 2);
    float* el = (float*)walloc((size_t)N * 4 * 4);
    float* er = (float*)walloc((size_t)N * 4 * 4);
    int* start = (int*)walloc((size_t)N * 4);
    int* endp = (int*)walloc((size_t)N * 4);
    int* col = (int*)walloc((size_t)E * 4);
    int* bcnt = (int*)walloc(1024 * 4);
    int* bbase = (int*)walloc(1024 * 4);
    int* bcursor = (int*)walloc(1024 * 4);
    int2* pairs = (int2*)walloc((size_t)E * 8);
    if (off > ws_size) return;

    const int TB = 256;
    const int nbkt = (N + 127) >> 7;            // 128 nodes per bucket
    const int nbe = (E + 8191) / 8192;
    transpose_w<<<3 * 65536 / TB, TB, 0, stream>>>(W_h, Wt);
    transpose_wo<<<48, TB, 0, stream>>>(W_o, Wt_o);
    hipMemsetAsync(bcnt, 0, (size_t)nbkt * 4, stream);
    bucket_count<<<nbe, TB, 0, stream>>>(edst, bcnt, E, nbkt);
    bucket_scan<<<1, TB, 0, stream>>>(bcnt, bbase, bcursor, nbkt);
    bucket_partition<<<nbe, TB, 0, stream>>>(esrc, edst, bcursor, pairs, E, nbkt);
    csr_bucket<<<nbkt, TB, 0, stream>>>(pairs, bbase, start, endp, col, N, E, nbkt);

    const int N2 = ((N / 2) + 3) & ~3;            // first-half node count, x4 aligned
    const int nbh1 = (N2 + 3) / 4;
    const int nbh2 = (N - N2 + 3) / 4;
    const int gemm_grid = ((N + 127) / 128) * 2;
    for (int l = 0; l < 3; ++l) {
        if (l == 0) {
            gemm_fused<true><<<gemm_grid, 256, 0, stream>>>(x, Wt, al_h, ar_h,
                                                            feat_bf, el, er, N);
        } else {
            gemm_fused<false><<<gemm_grid, 256, 0, stream>>>(h_bf, Wt + (size_t)l * 65536,
                                                             al_h + l * 256, ar_h + l * 256,
                                                             feat_bf, el, er, N);
        }
        const unsigned short* hin_bf = h_bf;
        const float* hin_f32 = (l == 0) ? x : nullptr;
        aggregate_hidden<<<nbh1, 256, 0, stream>>>(feat_bf, el, er, start, endp, col,
                                                   bias_h + l * 256, ln_g + l * 256,
                                                   ln_b + l * 256, hin_bf, hin_f32, h_bf, 0, N2);
        aggregate_hidden<<<nbh2, 256, 0, stream>>>(feat_bf, el, er, start, endp, col,
                                                   bias_h + l * 256, ln_g + l * 256,
                                                   ln_b + l * 256, hin_bf, hin_f32, h_bf, N2, N);
    }
    unsigned short* feat_o = feat_bf;  // reuse; OSTR=64 rows fit in 256-wide buffer
    float* elo = el;
    float* ero = er;
    gemm_out_mfma<<<(N + 127) / 128, 256, 0, stream>>>(h_bf, Wt_o, al_o, ar_o, feat_o, elo, ero, N);
    aggregate_out<<<nbh1, 256, 0, stream>>>(feat_o, elo, ero, start, endp, col, bias_o, out, 0, N2);
    aggregate_out<<<nbh2, 256, 0, stream>>>(feat_o, elo, ero, start, endp, col, bias_o, out, N2, N);
}

// Round 8
// 871.761 us; speedup vs baseline: 1.1514x; 1.1514x over previous
//
#include <hip/hip_runtime.h>
#include <math.h>

// GAT: 3 hidden GATConv layers (H=4, D=64, HID=256) + LN + leaky + residual,
// then output GATConv (H=1, C=40). N=100000 nodes, E=1600000 edges.
//
// Round 17: R16 zero-LDS GEMM reverted (110us, latency-bound, 2x overfetch).
// Diagnosis across 3 GEMM structures all ~80us (vs ~17us memory floor): the
// shared element is the epilogue's 64 scattered 2B C-stores/thread (partial-
// line L2 transactions + write-allocate RMW). This round: m97-style staged
// GEMM (gl_lds dbuf, 128x256, 8 waves - R11 known-good) + wave-private LDS
// repack epilogue: acc -> [16][68] fp32 slice (2-way banks, no barrier
// needed) -> ushort4 stores, 16 lanes = one full 128B line. Layer-0 A
// reg-staged with fp32->bf16 convert. Everything else = R15 (906us state).

#define NEG_SLOPE 0.2f

typedef __attribute__((ext_vector_type(8))) short bf16x8;
typedef __attribute__((ext_vector_type(4))) float floatx4;

__device__ __forceinline__ float leaky(float x) { return x >= 0.f ? x : NEG_SLOPE * x; }

__device__ __forceinline__ unsigned short f2bf(float f) {
    unsigned u = __builtin_bit_cast(unsigned, f);
    u += 0x7fffu + ((u >> 16) & 1u);  // RNE
    return (unsigned short)(u >> 16);
}
__device__ __forceinline__ float bf2f(unsigned short h) {
    unsigned u = ((unsigned)h) << 16;
    return __builtin_bit_cast(float, u);
}

// async global->LDS, 16B per lane (global_load_lds_dwordx4)
typedef const __attribute__((address_space(1))) unsigned int* as1_u32p;
typedef __attribute__((address_space(3))) unsigned int* as3_u32p;
__device__ __forceinline__ void gl_lds16(const void* g, void* l) {
    __builtin_amdgcn_global_load_lds((as1_u32p)g, (as3_u32p)l, 16, 0, 0);
}

// ---------------- bucketed CSR build ----------------
__global__ __launch_bounds__(256) void bucket_count(const int* __restrict__ dst,
                                                    int* __restrict__ bcnt, int E, int nbkt) {
    __shared__ int h[1024];
    for (int i = threadIdx.x; i < nbkt; i += 256) h[i] = 0;
    __syncthreads();
    const int base = blockIdx.x * 8192;
#pragma unroll 4
    for (int i = 0; i < 32; ++i) {
        int e = base + threadIdx.x + i * 256;
        if (e < E) atomicAdd(&h[dst[e] >> 7], 1);
    }
    __syncthreads();
    for (int i = threadIdx.x; i < nbkt; i += 256) {
        int v = h[i];
        if (v) atomicAdd(&bcnt[i], v);
    }
}

__global__ __launch_bounds__(256) void bucket_scan(const int* __restrict__ bcnt,
                                                   int* __restrict__ bbase,
                                                   int* __restrict__ bcursor, int nbkt) {
    __shared__ int s[256];
    const int t = threadIdx.x;
    int c[4];
    int tsum = 0;
#pragma unroll
    for (int j = 0; j < 4; ++j) {
        int i = t * 4 + j;
        c[j] = (i < nbkt) ? bcnt[i] : 0;
        tsum += c[j];
    }
    s[t] = tsum;
    __syncthreads();
    for (int off = 1; off < 256; off <<= 1) {
        int v = (t >= off) ? s[t - off] : 0;
        __syncthreads();
        s[t] += v;
        __syncthreads();
    }
    int excl = s[t] - tsum;
#pragma unroll
    for (int j = 0; j < 4; ++j) {
        int i = t * 4 + j;
        if (i < nbkt) {
            bbase[i] = excl;
            bcursor[i] = excl;
        }
        excl += c[j];
    }
}

__global__ __launch_bounds__(256) void bucket_partition(const int* __restrict__ src,
                                                        const int* __restrict__ dst,
                                                        int* __restrict__ bcursor,
                                                        int2* __restrict__ pairs, int E, int nbkt) {
    __shared__ int h[1024];
    __shared__ int basech[1024];
    for (int i = threadIdx.x; i < nbkt; i += 256) h[i] = 0;
    __syncthreads();
    const int base = blockIdx.x * 8192;
#pragma unroll 4
    for (int i = 0; i < 32; ++i) {
        int e = base + threadIdx.x + i * 256;
        if (e < E) atomicAdd(&h[dst[e] >> 7], 1);
    }
    __syncthreads();
    for (int i = threadIdx.x; i < nbkt; i += 256) {
        int v = h[i];
        basech[i] = v ? atomicAdd(&bcursor[i], v) : 0;
    }
    __syncthreads();
    for (int i = threadIdx.x; i < nbkt; i += 256) h[i] = 0;
    __syncthreads();
#pragma unroll 4
    for (int i = 0; i < 32; ++i) {
        int e = base + threadIdx.x + i * 256;
        if (e < E) {
            int d = dst[e], b = d >> 7;
            int r = atomicAdd(&h[b], 1);
            pairs[basech[b] + r] = make_int2(src[e], d);
        }
    }
}

__global__ __launch_bounds__(256) void csr_bucket(const int2* __restrict__ pairs,
                                                  const int* __restrict__ bbase,
                                                  int* __restrict__ start, int* __restrict__ endp,
                                                  int* __restrict__ col, int N, int E, int nbkt) {
    const int b = blockIdx.x;
    const int node0 = b << 7;
    int nc = N - node0;
    if (nc <= 0) return;
    if (nc > 128) nc = 128;
    __shared__ int cnt[128];
    __shared__ int s[128];
    const int t = threadIdx.x;
    if (t < 128) cnt[t] = 0;
    __syncthreads();
    const int ebase = bbase[b];
    const int eend = (b + 1 < nbkt) ? bbase[b + 1] : E;
    for (int e = ebase + t; e < eend; e += 256) {
        atomicAdd(&cnt[pairs[e].y - node0], 1);
    }
    __syncthreads();
    if (t < 128) s[t] = cnt[t];
    __syncthreads();
    for (int off = 1; off < 128; off <<= 1) {
        int v = 0;
        if (t < 128 && t >= off) v = s[t - off];
        __syncthreads();
        if (t < 128) s[t] += v;
        __syncthreads();
    }
    if (t < nc) {
        start[node0 + t] = ebase + s[t] - cnt[t];
        endp[node0 + t] = ebase + s[t];
    }
    if (t < 128) cnt[t] = s[t] - cnt[t];  // -> exclusive cursor
    __syncthreads();
    for (int e = ebase + t; e < eend; e += 256) {
        int2 pr = pairs[e];
        int r = atomicAdd(&cnt[pr.y - node0], 1);
        col[ebase + r] = pr.x;
    }
}

// ---------------- weight pre-transpose: Wt[l][n][k] = bf16(W[l][k][n]) ----------------
__global__ void transpose_w(const float* __restrict__ W, unsigned short* __restrict__ Wt) {
    int idx = blockIdx.x * 256 + threadIdx.x;
    int l = idx >> 16, r = idx & 65535;
    int k = r >> 8, n = r & 255;
    Wt[l * 65536 + n * 256 + k] = f2bf(W[l * 65536 + k * 256 + n]);
}

__global__ void transpose_wo(const float* __restrict__ W, unsigned short* __restrict__ Wt) {
    int idx = blockIdx.x * 256 + threadIdx.x;
    int n = idx >> 8, k = idx & 255;
    Wt[n * 256 + k] = (n < 40) ? f2bf(W[k * 40 + n]) : (unsigned short)0;
}

// ---------------- m97-style staged MFMA GEMM + coalesced epilogue + fused scores ----
// Block: 128 rows x 256 cols, 512 threads (8 waves, 64x64 each).
// Staging: gl_lds dwordx4 (bf16 A) / reg-convert (fp32 A), double-buffered.
// Epilogue: wave-private LDS repack -> ushort4 stores (128B line-granular).
template <bool F32>
__global__ __launch_bounds__(512, 4) void gemm_fused(
    const void* __restrict__ Av, const unsigned short* __restrict__ Wt,
    const float* __restrict__ al, const float* __restrict__ ar,
    unsigned short* __restrict__ Cb, float* __restrict__ el, float* __restrict__ er, int M) {
    const unsigned short* Ab = (const unsigned short*)Av;
    const float* Af = (const float*)Av;
    __shared__ unsigned short SMEM[24576];          // 48KB: staging, then repack
    unsigned short* As = SMEM;                      // [2][128*32]
    unsigned short* Bs = SMEM + 2 * 128 * 32;       // [2][256*32]
    const int tid = threadIdx.x;
    const int row0 = blockIdx.x * 128;
    const int lane = tid & 63, wid = tid >> 6;
    const int wm = (wid >> 2) * 64;   // 0 or 64
    const int wn = (wid & 3) * 64;    // 0,64,128,192
    const int q = lane >> 4, m = lane & 15;

    // staging geometry: 64 lanes x 16B = 1KB = 16 rows of [32] bf16
    const int arow = wid * 16 + (lane >> 2);
    const int brow0 = wid * 32 + (lane >> 2);
    const int kx = (lane & 3) * 8;
    const int agr = (row0 + arow < M) ? (row0 + arow) : (M - 1);

    auto stage = [&](int buf, int kb) {
        if constexpr (F32) {
            const float* p = Af + (size_t)agr * 256 + kb + kx;
            float4 f0 = *(const float4*)p;
            float4 f1 = *(const float4*)(p + 4);
            bf16x8 v;
            v[0] = (short)f2bf(f0.x); v[1] = (short)f2bf(f0.y);
            v[2] = (short)f2bf(f0.z); v[3] = (short)f2bf(f0.w);
            v[4] = (short)f2bf(f1.x); v[5] = (short)f2bf(f1.y);
            v[6] = (short)f2bf(f1.z); v[7] = (short)f2bf(f1.w);
            *(bf16x8*)&As[buf * 128 * 32 + arow * 32 + kx] = v;
        } else {
            gl_lds16(Ab + (size_t)agr * 256 + kb + kx, &As[buf * 128 * 32 + arow * 32 + kx]);
        }
        gl_lds16(Wt + (size_t)brow0 * 256 + kb + kx, &Bs[buf * 256 * 32 + brow0 * 32 + kx]);
        gl_lds16(Wt + (size_t)(brow0 + 16) * 256 + kb + kx,
                 &Bs[buf * 256 * 32 + (brow0 + 16) * 32 + kx]);
    };

    floatx4 acc[4][4] = {};
    stage(0, 0);
    __syncthreads();
    int cur = 0;
    for (int kb = 0; kb < 256; kb += 32) {
        int nkb = kb + 32;
        if (nkb < 256) stage(cur ^ 1, nkb);
        bf16x8 af[4], bfr[4];
#pragma unroll
        for (int i = 0; i < 4; ++i) {
            af[i] = *(const bf16x8*)&As[cur * 128 * 32 + (wm + i * 16 + m) * 32 + q * 8];
            bfr[i] = *(const bf16x8*)&Bs[cur * 256 * 32 + (wn + i * 16 + m) * 32 + q * 8];
        }
#pragma unroll
        for (int i = 0; i < 4; ++i)
#pragma unroll
            for (int j = 0; j < 4; ++j)
                acc[i][j] = __builtin_amdgcn_mfma_f32_16x16x32_bf16(af[i], bfr[j], acc[i][j], 0, 0, 0);
        __syncthreads();   // drains vmcnt+lgkmcnt: next buffer ready
        cur ^= 1;
    }
    // After the final barrier all waves are done with As/Bs -> reuse as
    // wave-private repack scratch: [16][68] fp32 per wave (4.25KB x 8 = 34KB).
    float* rep = (float*)SMEM + wid * 1088;
    const int c = lane & 15;
#pragma unroll
    for (int i = 0; i < 4; ++i) {
#pragma unroll
        for (int j = 0; j < 4; ++j)
#pragma unroll
            for (int r = 0; r < 4; ++r)
                rep[(q * 4 + r) * 68 + j * 16 + c] = acc[i][j][r];
        // wave-synchronous RAW through LDS (compiler inserts lgkmcnt)
#pragma unroll
        for (int p = 0; p < 4; ++p) {
            int row16 = p * 4 + (lane >> 4);
            int c4 = (lane & 15) * 4;
            float4 v = *(const float4*)&rep[row16 * 68 + c4];
            int grow = row0 + wm + i * 16 + row16;
            if (grow < M) {
                ushort4 o;
                o.x = f2bf(v.x); o.y = f2bf(v.y); o.z = f2bf(v.z); o.w = f2bf(v.w);
                *(ushort4*)(Cb + (size_t)grow * 256 + wn + c4) = o;  // 16 lanes = 128B line
            }
        }
    }

    // fused head dots from fp32 accumulators
    const int head = wid & 3;
    const float* alh = al + head * 64;
    const float* arh = ar + head * 64;
    float a0 = alh[c], a1 = alh[16 + c], a2 = alh[32 + c], a3 = alh[48 + c];
    float r0 = arh[c], r1 = arh[16 + c], r2 = arh[32 + c], r3 = arh[48 + c];
#pragma unroll
    for (int i = 0; i < 4; ++i)
#pragma unroll
        for (int r = 0; r < 4; ++r) {
            float pel = acc[i][0][r] * a0 + acc[i][1][r] * a1 + acc[i][2][r] * a2 + acc[i][3][r] * a3;
            float per = acc[i][0][r] * r0 + acc[i][1][r] * r1 + acc[i][2][r] * r2 + acc[i][3][r] * r3;
#pragma unroll
            for (int off = 8; off >= 1; off >>= 1) {
                pel += __shfl_xor(pel, off);
                per += __shfl_xor(per, off);
            }
            if (c == 0) {
                int grow = row0 + wm + i * 16 + q * 4 + r;
                if (grow < M) {
                    el[(size_t)grow * 4 + head] = pel;
                    er[(size_t)grow * 4 + head] = per;
                }
            }
        }
}

// ---------------- output MFMA GEMM: feat_o[N,64pad] bf16 = h_bf[N,256] @ W_o ----------------
#define LDSK 40
#define BSTRIDE 264
#define OSTR 64   // feat_o row stride (elements): 128B line-aligned
__global__ __launch_bounds__(256) void gemm_out_mfma(const unsigned short* __restrict__ h,
                                                     const unsigned short* __restrict__ Wt,
                                                     const float* __restrict__ alo,
                                                     const float* __restrict__ aro,
                                                     unsigned short* __restrict__ feat_o,
                                                     float* __restrict__ elo,
                                                     float* __restrict__ ero, int N) {
    __shared__ unsigned short As[128 * LDSK];
    __shared__ unsigned short Bs[48 * BSTRIDE];
    const int tid = threadIdx.x;
    const int row0 = blockIdx.x * 128;
    const int lane = tid & 63, wid = tid >> 6;

#pragma unroll
    for (int i = 0; i < 6; ++i) {
        int f = tid + 256 * i;
        int n = f >> 5, kk = (f & 31) * 8;
        *(bf16x8*)&Bs[n * BSTRIDE + kk] = *(const bf16x8*)(Wt + n * 256 + kk);
    }
    __syncthreads();

    floatx4 acc[2][3] = {};
    for (int kb = 0; kb < 256; kb += 32) {
#pragma unroll
        for (int i = 0; i < 2; ++i) {
            int idx = tid + 256 * i;
            int r = idx >> 2, k8 = (idx & 3) * 8;
            int gr = row0 + r;
            bf16x8 v = {};
            if (gr < N) v = *(const bf16x8*)(h + (size_t)gr * 256 + kb + k8);
            *(bf16x8*)&As[r * LDSK + k8] = v;
        }
        __syncthreads();
        const int q = lane >> 4, m = lane & 15;
        bf16x8 af[2], bfr[3];
#pragma unroll
        for (int i = 0; i < 2; ++i)
            af[i] = *(const bf16x8*)&As[(wid * 32 + i * 16 + m) * LDSK + q * 8];
#pragma unroll
        for (int j = 0; j < 3; ++j)
            bfr[j] = *(const bf16x8*)&Bs[(j * 16 + m) * BSTRIDE + kb + q * 8];
#pragma unroll
        for (int i = 0; i < 2; ++i)
#pragma unroll
            for (int j = 0; j < 3; ++j)
                acc[i][j] = __builtin_amdgcn_mfma_f32_16x16x32_bf16(af[i], bfr[j], acc[i][j], 0, 0, 0);
        __syncthreads();
    }

    const int q = lane >> 4, c = lane & 15;
#pragma unroll
    for (int i = 0; i < 2; ++i)
#pragma unroll
        for (int j = 0; j < 3; ++j)
#pragma unroll
            for (int r = 0; r < 4; ++r) {
                int grow = row0 + wid * 32 + i * 16 + q * 4 + r;
                int gcol = j * 16 + c;
                if (grow < N && gcol < 40) feat_o[(size_t)grow * OSTR + gcol] = f2bf(acc[i][j][r]);
            }

    float aj[3], rj[3];
#pragma unroll
    for (int j = 0; j < 3; ++j) {
        int gcol = j * 16 + c;
        aj[j] = gcol < 40 ? alo[gcol] : 0.f;
        rj[j] = gcol < 40 ? aro[gcol] : 0.f;
    }
#pragma unroll
    for (int i = 0; i < 2; ++i)
#pragma unroll
        for (int r = 0; r < 4; ++r) {
            float pl = acc[i][0][r] * aj[0] + acc[i][1][r] * aj[1] + acc[i][2][r] * aj[2];
            float pr = acc[i][0][r] * rj[0] + acc[i][1][r] * rj[1] + acc[i][2][r] * rj[2];
#pragma unroll
            for (int off = 8; off >= 1; off >>= 1) {
                pl += __shfl_xor(pl, off);
                pr += __shfl_xor(pr, off);
            }
            if (c == 0) {
                int grow = row0 + wid * 32 + i * 16 + q * 4 + r;
                if (grow < N) {
                    elo[grow] = pl;
                    ero[grow] = pr;
                }
            }
        }
}

// ---------------- hidden-layer aggregation: single pass + fused epilogue ----------------
__global__ __launch_bounds__(256) void aggregate_hidden(
    const unsigned short* __restrict__ feat, const float* __restrict__ el,
    const float* __restrict__ er, const int* __restrict__ start, const int* __restrict__ endp,
    const int* __restrict__ col, const float* __restrict__ bias, const float* __restrict__ lng,
    const float* __restrict__ lnb, const unsigned short* __restrict__ h_in,
    const float* __restrict__ h_in_f32,
    unsigned short* __restrict__ h_out, int node0, int nend) {
    int node = node0 + blockIdx.x * 4 + (threadIdx.x >> 6);
    int lane = threadIdx.x & 63;
    if (node >= nend) return;
    int begin = __builtin_amdgcn_readfirstlane(start[node]);
    int end = __builtin_amdgcn_readfirstlane(endp[node]);
    const int head = lane >> 4;
    const float erh = er[(size_t)node * 4 + head];

    const int ch = lane * 4;
    const unsigned short* fbase = feat + ch;
    const size_t hstr = 256;
    float4 acc = {0.f, 0.f, 0.f, 0.f};
    float ssum = 0.f;
    int e = begin;
    for (; e + 7 < end; e += 8) {
        int sA = col[e], sB = col[e + 1], sC = col[e + 2], sD = col[e + 3];
        int sE = col[e + 4], sF = col[e + 5], sG = col[e + 6], sH = col[e + 7];
        float eA = el[(size_t)sA * 4 + head];
        float eB = el[(size_t)sB * 4 + head];
        float eC = el[(size_t)sC * 4 + head];
        float eD = el[(size_t)sD * 4 + head];
        float eE = el[(size_t)sE * 4 + head];
        float eF = el[(size_t)sF * 4 + head];
        float eG = el[(size_t)sG * 4 + head];
        float eH = el[(size_t)sH * 4 + head];
        ushort4 uA = *(const ushort4*)(fbase + sA * hstr);
        ushort4 uB = *(const ushort4*)(fbase + sB * hstr);
        ushort4 uC = *(const ushort4*)(fbase + sC * hstr);
        ushort4 uD = *(const ushort4*)(fbase + sD * hstr);
        ushort4 uE = *(const ushort4*)(fbase + sE * hstr);
        ushort4 uF = *(const ushort4*)(fbase + sF * hstr);
        ushort4 uG = *(const ushort4*)(fbase + sG * hstr);
        ushort4 uH = *(const ushort4*)(fbase + sH * hstr);
        float wA = __expf(leaky(eA + erh));
        float wB = __expf(leaky(eB + erh));
        float wC = __expf(leaky(eC + erh));
        float wD = __expf(leaky(eD + erh));
        float wE = __expf(leaky(eE + erh));
        float wF = __expf(leaky(eF + erh));
        float wG = __expf(leaky(eG + erh));
        float wH = __expf(leaky(eH + erh));
        ssum += wA + wB + wC + wD + wE + wF + wG + wH;
        acc.x = fmaf(wA, bf2f(uA.x), acc.x); acc.y = fmaf(wA, bf2f(uA.y), acc.y);
        acc.z = fmaf(wA, bf2f(uA.z), acc.z); acc.w = fmaf(wA, bf2f(uA.w), acc.w);
        acc.x = fmaf(wB, bf2f(uB.x), acc.x); acc.y = fmaf(wB, bf2f(uB.y), acc.y);
        acc.z = fmaf(wB, bf2f(uB.z), acc.z); acc.w = fmaf(wB, bf2f(uB.w), acc.w);
        acc.x = fmaf(wC, bf2f(uC.x), acc.x); acc.y = fmaf(wC, bf2f(uC.y), acc.y);
        acc.z = fmaf(wC, bf2f(uC.z), acc.z); acc.w = fmaf(wC, bf2f(uC.w), acc.w);
        acc.x = fmaf(wD, bf2f(uD.x), acc.x); acc.y = fmaf(wD, bf2f(uD.y), acc.y);
        acc.z = fmaf(wD, bf2f(uD.z), acc.z); acc.w = fmaf(wD, bf2f(uD.w), acc.w);
        acc.x = fmaf(wE, bf2f(uE.x), acc.x); acc.y = fmaf(wE, bf2f(uE.y), acc.y);
        acc.z = fmaf(wE, bf2f(uE.z), acc.z); acc.w = fmaf(wE, bf2f(uE.w), acc.w);
        acc.x = fmaf(wF, bf2f(uF.x), acc.x); acc.y = fmaf(wF, bf2f(uF.y), acc.y);
        acc.z = fmaf(wF, bf2f(uF.z), acc.z); acc.w = fmaf(wF, bf2f(uF.w), acc.w);
        acc.x = fmaf(wG, bf2f(uG.x), acc.x); acc.y = fmaf(wG, bf2f(uG.y), acc.y);
        acc.z = fmaf(wG, bf2f(uG.z), acc.z); acc.w = fmaf(wG, bf2f(uG.w), acc.w);
        acc.x = fmaf(wH, bf2f(uH.x), acc.x); acc.y = fmaf(wH, bf2f(uH.y), acc.y);
        acc.z = fmaf(wH, bf2f(uH.z), acc.z); acc.w = fmaf(wH, bf2f(uH.w), acc.w);
    }
    for (; e < end; ++e) {
        int sA = col[e];
        float wA = __expf(leaky(el[(size_t)sA * 4 + head] + erh));
        ushort4 uA = *(const ushort4*)(fbase + sA * hstr);
        ssum += wA;
        acc.x = fmaf(wA, bf2f(uA.x), acc.x); acc.y = fmaf(wA, bf2f(uA.y), acc.y);
        acc.z = fmaf(wA, bf2f(uA.z), acc.z); acc.w = fmaf(wA, bf2f(uA.w), acc.w);
    }
    float inv = ssum > 0.f ? 1.f / ssum : 0.f;
    acc.x *= inv; acc.y *= inv; acc.z *= inv; acc.w *= inv;

    float4 bb = *(const float4*)(bias + ch);
    float x0 = acc.x + bb.x, x1 = acc.y + bb.y, x2 = acc.z + bb.z, x3 = acc.w + bb.w;
    x0 = x0 > 0.f ? x0 : expm1f(x0);
    x1 = x1 > 0.f ? x1 : expm1f(x1);
    x2 = x2 > 0.f ? x2 : expm1f(x2);
    x3 = x3 > 0.f ? x3 : expm1f(x3);
    float lsum = x0 + x1 + x2 + x3;
    float lsq = x0 * x0 + x1 * x1 + x2 * x2 + x3 * x3;
#pragma unroll
    for (int off = 32; off >= 1; off >>= 1) {
        lsum += __shfl_xor(lsum, off);
        lsq += __shfl_xor(lsq, off);
    }
    float mu = lsum * (1.f / 256.f);
    float var = lsq * (1.f / 256.f) - mu * mu;
    float rstd = rsqrtf(var + 1e-5f);
    float4 g4 = *(const float4*)(lng + ch);
    float4 b4 = *(const float4*)(lnb + ch);
    float rx, ry, rz, rw;
    if (h_in_f32) {
        float4 hf = *(const float4*)(h_in_f32 + (size_t)node * 256 + ch);
        rx = hf.x; ry = hf.y; rz = hf.z; rw = hf.w;
    } else {
        ushort4 hi = *(const ushort4*)(h_in + (size_t)node * 256 + ch);
        rx = bf2f(hi.x); ry = bf2f(hi.y); rz = bf2f(hi.z); rw = bf2f(hi.w);
    }
    float y0 = (x0 - mu) * rstd * g4.x + b4.x;
    float y1 = (x1 - mu) * rstd * g4.y + b4.y;
    float y2 = (x2 - mu) * rstd * g4.z + b4.z;
    float y3 = (x3 - mu) * rstd * g4.w + b4.w;
    y0 = (y0 >= 0.f ? y0 : 0.2f * y0) + rx;
    y1 = (y1 >= 0.f ? y1 : 0.2f * y1) + ry;
    y2 = (y2 >= 0.f ? y2 : 0.2f * y2) + rz;
    y3 = (y3 >= 0.f ? y3 : 0.2f * y3) + rw;
    ushort4 o;
    o.x = f2bf(y0); o.y = f2bf(y1); o.z = f2bf(y2); o.w = f2bf(y3);
    *(ushort4*)(h_out + (size_t)node * 256 + ch) = o;
}

// ---------------- output aggregation: logits[N,40], single pass ----------------
__global__ __launch_bounds__(256) void aggregate_out(const unsigned short* __restrict__ feat_o,
                                                     const float* __restrict__ elo,
                                                     const float* __restrict__ ero,
                                                     const int* __restrict__ start,
                                                     const int* __restrict__ endp,
                                                     const int* __restrict__ col,
                                                     const float* __restrict__ bias_o,
                                                     float* __restrict__ out, int node0, int nend) {
    int node = node0 + blockIdx.x * 4 + (threadIdx.x >> 6);
    int lane = threadIdx.x & 63;
    if (node >= nend) return;
    int begin = __builtin_amdgcn_readfirstlane(start[node]);
    int end = __builtin_amdgcn_readfirstlane(endp[node]);
    float ern = ero[node];
    int cc = lane < 40 ? lane : 0;
    float acc = 0.f, ssum = 0.f;
    int e = begin;
    for (; e + 7 < end; e += 8) {
        int sA = col[e], sB = col[e + 1], sC = col[e + 2], sD = col[e + 3];
        int sE = col[e + 4], sF = col[e + 5], sG = col[e + 6], sH = col[e + 7];
        float eA = elo[sA], eB = elo[sB], eC = elo[sC], eD = elo[sD];
        float eE = elo[sE], eF = elo[sF], eG = elo[sG], eH = elo[sH];
        unsigned short fA = feat_o[(size_t)sA * OSTR + cc];
        unsigned short fB = feat_o[(size_t)sB * OSTR + cc];
        unsigned short fC = feat_o[(size_t)sC * OSTR + cc];
        unsigned short fD = feat_o[(size_t)sD * OSTR + cc];
        unsigned short fE = feat_o[(size_t)sE * OSTR + cc];
        unsigned short fF = feat_o[(size_t)sF * OSTR + cc];
        unsigned short fG = feat_o[(size_t)sG * OSTR + cc];
        unsigned short fH = feat_o[(size_t)sH * OSTR + cc];
        float wA = __expf(leaky(eA + ern));
        float wB = __expf(leaky(eB + ern));
        float wC = __expf(leaky(eC + ern));
        float wD = __expf(leaky(eD + ern));
        float wE = __expf(leaky(eE + ern));
        float wF = __expf(leaky(eF + ern));
        float wG = __expf(leaky(eG + ern));
        float wH = __expf(leaky(eH + ern));
        ssum += wA + wB + wC + wD + wE + wF + wG + wH;
        acc = fmaf(wA, bf2f(fA), acc);
        acc = fmaf(wB, bf2f(fB), acc);
        acc = fmaf(wC, bf2f(fC), acc);
        acc = fmaf(wD, bf2f(fD), acc);
        acc = fmaf(wE, bf2f(fE), acc);
        acc = fmaf(wF, bf2f(fF), acc);
        acc = fmaf(wG, bf2f(fG), acc);
        acc = fmaf(wH, bf2f(fH), acc);
    }
    for (; e < end; ++e) {
        int sA = col[e];
        float wA = __expf(leaky(elo[sA] + ern));
        ssum += wA;
        acc = fmaf(wA, bf2f(feat_o[(size_t)sA * OSTR + cc]), acc);
    }
    float inv = ssum > 0.f ? 1.f / ssum : 0.f;
    if (lane < 40) out[(size_t)node * 40 + lane] = acc * inv + bias_o[lane];
}

// ---------------- launcher ----------------
extern "C" void kernel_launch(void* const* d_in, const int* in_sizes, int n_in,
                              void* d_out, int out_size, void* d_ws, size_t ws_size,
                              hipStream_t stream) {
    const float* x = (const float*)d_in[0];
    const float* W_h = (const float*)d_in[1];
    const float* al_h = (const float*)d_in[2];
    const float* ar_h = (const float*)d_in[3];
    const float* bias_h = (const float*)d_in[4];
    const float* ln_g = (const float*)d_in[5];
    const float* ln_b = (const float*)d_in[6];
    const float* W_o = (const float*)d_in[7];
    const float* al_o = (const float*)d_in[8];
    const float* ar_o = (const float*)d_in[9];
    const float* bias_o = (const float*)d_in[10];
    const int* esrc = (const int*)d_in[11];
    const int* edst = (const int*)d_in[12];
    const int N = in_sizes[0] / 256;
    const int E = in_sizes[11];
    float* out = (float*)d_out;

    char* ws = (char*)d_ws;
    size_t off = 0;
    auto walloc = [&](size_t bytes) -> void* {
        void* p = ws + off;
        off += (bytes + 255) & ~(size_t)255;
        return p;
    };
    unsigned short* h_bf = (unsigned short*)walloc((size_t)N * 256 * 2);
    unsigned short* feat_bf = (unsigned short*)walloc((size_t)N * 256 * 2);
    unsigned short* Wt = (unsigned short*)walloc((size_t)3 * 65536 * 2);
    unsigned short* Wt_o = (unsigned short*)walloc((size_t)48 * 256 * 2);
    float* el = (float*)walloc((size_t)N * 4 * 4);
    float* er = (float*)walloc((size_t)N * 4 * 4);
    int* start = (int*)walloc((size_t)N * 4);
    int* endp = (int*)walloc((size_t)N * 4);
    int* col = (int*)walloc((size_t)E * 4);
    int* bcnt = (int*)walloc(1024 * 4);
    int* bbase = (int*)walloc(1024 * 4);
    int* bcursor = (int*)walloc(1024 * 4);
    int2* pairs = (int2*)walloc((size_t)E * 8);
    if (off > ws_size) return;

    const int TB = 256;
    const int nbkt = (N + 127) >> 7;            // 128 nodes per bucket
    const int nbe = (E + 8191) / 8192;
    transpose_w<<<3 * 65536 / TB, TB, 0, stream>>>(W_h, Wt);
    transpose_wo<<<48, TB, 0, stream>>>(W_o, Wt_o);
    hipMemsetAsync(bcnt, 0, (size_t)nbkt * 4, stream);
    bucket_count<<<nbe, TB, 0, stream>>>(edst, bcnt, E, nbkt);
    bucket_scan<<<1, TB, 0, stream>>>(bcnt, bbase, bcursor, nbkt);
    bucket_partition<<<nbe, TB, 0, stream>>>(esrc, edst, bcursor, pairs, E, nbkt);
    csr_bucket<<<nbkt, TB, 0, stream>>>(pairs, bbase, start, endp, col, N, E, nbkt);

    const int N2 = ((N / 2) + 3) & ~3;            // first-half node count, x4 aligned
    const int nbh1 = (N2 + 3) / 4;
    const int nbh2 = (N - N2 + 3) / 4;
    const int gemm_grid = (N + 127) / 128;
    for (int l = 0; l < 3; ++l) {
        if (l == 0) {
            gemm_fused<true><<<gemm_grid, 512, 0, stream>>>(x, Wt, al_h, ar_h,
                                                            feat_bf, el, er, N);
        } else {
            gemm_fused<false><<<gemm_grid, 512, 0, stream>>>(h_bf, Wt + (size_t)l * 65536,
                                                             al_h + l * 256, ar_h + l * 256,
                                                             feat_bf, el, er, N);
        }
        const unsigned short* hin_bf = h_bf;
        const float* hin_f32 = (l == 0) ? x : nullptr;
        aggregate_hidden<<<nbh1, 256, 0, stream>>>(feat_bf, el, er, start, endp, col,
                                                   bias_h + l * 256, ln_g + l * 256,
                                                   ln_b + l * 256, hin_bf, hin_f32, h_bf, 0, N2);
        aggregate_hidden<<<nbh2, 256, 0, stream>>>(feat_bf, el, er, start, endp, col,
                                                   bias_h + l * 256, ln_g + l * 256,
                                                   ln_b + l * 256, hin_bf, hin_f32, h_bf, N2, N);
    }
    unsigned short* feat_o = feat_bf;  // reuse; OSTR=64 rows fit in 256-wide buffer
    float* elo = el;
    float* ero = er;
    gemm_out_mfma<<<(N + 127) / 128, 256, 0, stream>>>(h_bf, Wt_o, al_o, ar_o, feat_o, elo, ero, N);
    aggregate_out<<<nbh1, 256, 0, stream>>>(feat_o, elo, ero, start, endp, col, bias_o, out, 0, N2);
    aggregate_out<<<nbh2, 256, 0, stream>>>(feat_o, elo, ero, start, endp, col, bias_o, out, N2, N);
}

// Round 9
// 865.267 us; speedup vs baseline: 1.1601x; 1.0075x over previous
//
#include <hip/hip_runtime.h>
#include <math.h>

// GAT: 3 hidden GATConv layers (H=4, D=64, HID=256) + LN + leaky + residual,
// then output GATConv (H=1, C=40). N=100000 nodes, E=1600000 edges.
//
// Round 18: launch/tail harvesting. R17's coalesced-epilogue GEMM (-34us)
// kept. The instrumentation half-splits (aggregate_hidden x2/layer,
// aggregate_out x2) are merged back - each split pair paid a full extra
// dispatch tail on the serial stream. Transpose kernels merged. Side
// effect: merged aggregates (~150us) push the largest gemm_fused into the
// top-5 for final visibility. Everything else unchanged from R17 (872us).

#define NEG_SLOPE 0.2f

typedef __attribute__((ext_vector_type(8))) short bf16x8;
typedef __attribute__((ext_vector_type(4))) float floatx4;

__device__ __forceinline__ float leaky(float x) { return x >= 0.f ? x : NEG_SLOPE * x; }

__device__ __forceinline__ unsigned short f2bf(float f) {
    unsigned u = __builtin_bit_cast(unsigned, f);
    u += 0x7fffu + ((u >> 16) & 1u);  // RNE
    return (unsigned short)(u >> 16);
}
__device__ __forceinline__ float bf2f(unsigned short h) {
    unsigned u = ((unsigned)h) << 16;
    return __builtin_bit_cast(float, u);
}

// async global->LDS, 16B per lane (global_load_lds_dwordx4)
typedef const __attribute__((address_space(1))) unsigned int* as1_u32p;
typedef __attribute__((address_space(3))) unsigned int* as3_u32p;
__device__ __forceinline__ void gl_lds16(const void* g, void* l) {
    __builtin_amdgcn_global_load_lds((as1_u32p)g, (as3_u32p)l, 16, 0, 0);
}

// ---------------- bucketed CSR build ----------------
__global__ __launch_bounds__(256) void bucket_count(const int* __restrict__ dst,
                                                    int* __restrict__ bcnt, int E, int nbkt) {
    __shared__ int h[1024];
    for (int i = threadIdx.x; i < nbkt; i += 256) h[i] = 0;
    __syncthreads();
    const int base = blockIdx.x * 8192;
#pragma unroll 4
    for (int i = 0; i < 32; ++i) {
        int e = base + threadIdx.x + i * 256;
        if (e < E) atomicAdd(&h[dst[e] >> 7], 1);
    }
    __syncthreads();
    for (int i = threadIdx.x; i < nbkt; i += 256) {
        int v = h[i];
        if (v) atomicAdd(&bcnt[i], v);
    }
}

__global__ __launch_bounds__(256) void bucket_scan(const int* __restrict__ bcnt,
                                                   int* __restrict__ bbase,
                                                   int* __restrict__ bcursor, int nbkt) {
    __shared__ int s[256];
    const int t = threadIdx.x;
    int c[4];
    int tsum = 0;
#pragma unroll
    for (int j = 0; j < 4; ++j) {
        int i = t * 4 + j;
        c[j] = (i < nbkt) ? bcnt[i] : 0;
        tsum += c[j];
    }
    s[t] = tsum;
    __syncthreads();
    for (int off = 1; off < 256; off <<= 1) {
        int v = (t >= off) ? s[t - off] : 0;
        __syncthreads();
        s[t] += v;
        __syncthreads();
    }
    int excl = s[t] - tsum;
#pragma unroll
    for (int j = 0; j < 4; ++j) {
        int i = t * 4 + j;
        if (i < nbkt) {
            bbase[i] = excl;
            bcursor[i] = excl;
        }
        excl += c[j];
    }
}

__global__ __launch_bounds__(256) void bucket_partition(const int* __restrict__ src,
                                                        const int* __restrict__ dst,
                                                        int* __restrict__ bcursor,
                                                        int2* __restrict__ pairs, int E, int nbkt) {
    __shared__ int h[1024];
    __shared__ int basech[1024];
    for (int i = threadIdx.x; i < nbkt; i += 256) h[i] = 0;
    __syncthreads();
    const int base = blockIdx.x * 8192;
#pragma unroll 4
    for (int i = 0; i < 32; ++i) {
        int e = base + threadIdx.x + i * 256;
        if (e < E) atomicAdd(&h[dst[e] >> 7], 1);
    }
    __syncthreads();
    for (int i = threadIdx.x; i < nbkt; i += 256) {
        int v = h[i];
        basech[i] = v ? atomicAdd(&bcursor[i], v) : 0;
    }
    __syncthreads();
    for (int i = threadIdx.x; i < nbkt; i += 256) h[i] = 0;
    __syncthreads();
#pragma unroll 4
    for (int i = 0; i < 32; ++i) {
        int e = base + threadIdx.x + i * 256;
        if (e < E) {
            int d = dst[e], b = d >> 7;
            int r = atomicAdd(&h[b], 1);
            pairs[basech[b] + r] = make_int2(src[e], d);
        }
    }
}

__global__ __launch_bounds__(256) void csr_bucket(const int2* __restrict__ pairs,
                                                  const int* __restrict__ bbase,
                                                  int* __restrict__ start, int* __restrict__ endp,
                                                  int* __restrict__ col, int N, int E, int nbkt) {
    const int b = blockIdx.x;
    const int node0 = b << 7;
    int nc = N - node0;
    if (nc <= 0) return;
    if (nc > 128) nc = 128;
    __shared__ int cnt[128];
    __shared__ int s[128];
    const int t = threadIdx.x;
    if (t < 128) cnt[t] = 0;
    __syncthreads();
    const int ebase = bbase[b];
    const int eend = (b + 1 < nbkt) ? bbase[b + 1] : E;
    for (int e = ebase + t; e < eend; e += 256) {
        atomicAdd(&cnt[pairs[e].y - node0], 1);
    }
    __syncthreads();
    if (t < 128) s[t] = cnt[t];
    __syncthreads();
    for (int off = 1; off < 128; off <<= 1) {
        int v = 0;
        if (t < 128 && t >= off) v = s[t - off];
        __syncthreads();
        if (t < 128) s[t] += v;
        __syncthreads();
    }
    if (t < nc) {
        start[node0 + t] = ebase + s[t] - cnt[t];
        endp[node0 + t] = ebase + s[t];
    }
    if (t < 128) cnt[t] = s[t] - cnt[t];  // -> exclusive cursor
    __syncthreads();
    for (int e = ebase + t; e < eend; e += 256) {
        int2 pr = pairs[e];
        int r = atomicAdd(&cnt[pr.y - node0], 1);
        col[ebase + r] = pr.x;
    }
}

// ---------------- weight pre-transpose (merged): Wt + Wt_o ----------------
__global__ void transpose_all(const float* __restrict__ W, unsigned short* __restrict__ Wt,
                              const float* __restrict__ Wo, unsigned short* __restrict__ Wt_o) {
    int idx = blockIdx.x * 256 + threadIdx.x;
    if (idx < 3 * 65536) {
        int l = idx >> 16, r = idx & 65535;
        int k = r >> 8, n = r & 255;
        Wt[l * 65536 + n * 256 + k] = f2bf(W[l * 65536 + k * 256 + n]);
    } else {
        int j = idx - 3 * 65536;           // 48*256 entries
        int n = j >> 8, k = j & 255;
        Wt_o[n * 256 + k] = (n < 40) ? f2bf(Wo[k * 40 + n]) : (unsigned short)0;
    }
}

// ---------------- m97-style staged MFMA GEMM + coalesced epilogue + fused scores ----
template <bool F32>
__global__ __launch_bounds__(512, 4) void gemm_fused(
    const void* __restrict__ Av, const unsigned short* __restrict__ Wt,
    const float* __restrict__ al, const float* __restrict__ ar,
    unsigned short* __restrict__ Cb, float* __restrict__ el, float* __restrict__ er, int M) {
    const unsigned short* Ab = (const unsigned short*)Av;
    const float* Af = (const float*)Av;
    __shared__ unsigned short SMEM[24576];          // 48KB: staging, then repack
    unsigned short* As = SMEM;                      // [2][128*32]
    unsigned short* Bs = SMEM + 2 * 128 * 32;       // [2][256*32]
    const int tid = threadIdx.x;
    const int row0 = blockIdx.x * 128;
    const int lane = tid & 63, wid = tid >> 6;
    const int wm = (wid >> 2) * 64;   // 0 or 64
    const int wn = (wid & 3) * 64;    // 0,64,128,192
    const int q = lane >> 4, m = lane & 15;

    const int arow = wid * 16 + (lane >> 2);
    const int brow0 = wid * 32 + (lane >> 2);
    const int kx = (lane & 3) * 8;
    const int agr = (row0 + arow < M) ? (row0 + arow) : (M - 1);

    auto stage = [&](int buf, int kb) {
        if constexpr (F32) {
            const float* p = Af + (size_t)agr * 256 + kb + kx;
            float4 f0 = *(const float4*)p;
            float4 f1 = *(const float4*)(p + 4);
            bf16x8 v;
            v[0] = (short)f2bf(f0.x); v[1] = (short)f2bf(f0.y);
            v[2] = (short)f2bf(f0.z); v[3] = (short)f2bf(f0.w);
            v[4] = (short)f2bf(f1.x); v[5] = (short)f2bf(f1.y);
            v[6] = (short)f2bf(f1.z); v[7] = (short)f2bf(f1.w);
            *(bf16x8*)&As[buf * 128 * 32 + arow * 32 + kx] = v;
        } else {
            gl_lds16(Ab + (size_t)agr * 256 + kb + kx, &As[buf * 128 * 32 + arow * 32 + kx]);
        }
        gl_lds16(Wt + (size_t)brow0 * 256 + kb + kx, &Bs[buf * 256 * 32 + brow0 * 32 + kx]);
        gl_lds16(Wt + (size_t)(brow0 + 16) * 256 + kb + kx,
                 &Bs[buf * 256 * 32 + (brow0 + 16) * 32 + kx]);
    };

    floatx4 acc[4][4] = {};
    stage(0, 0);
    __syncthreads();
    int cur = 0;
    for (int kb = 0; kb < 256; kb += 32) {
        int nkb = kb + 32;
        if (nkb < 256) stage(cur ^ 1, nkb);
        bf16x8 af[4], bfr[4];
#pragma unroll
        for (int i = 0; i < 4; ++i) {
            af[i] = *(const bf16x8*)&As[cur * 128 * 32 + (wm + i * 16 + m) * 32 + q * 8];
            bfr[i] = *(const bf16x8*)&Bs[cur * 256 * 32 + (wn + i * 16 + m) * 32 + q * 8];
        }
#pragma unroll
        for (int i = 0; i < 4; ++i)
#pragma unroll
            for (int j = 0; j < 4; ++j)
                acc[i][j] = __builtin_amdgcn_mfma_f32_16x16x32_bf16(af[i], bfr[j], acc[i][j], 0, 0, 0);
        __syncthreads();   // drains vmcnt+lgkmcnt: next buffer ready
        cur ^= 1;
    }
    // reuse staging LDS as wave-private repack scratch: [16][68] fp32 per wave
    float* rep = (float*)SMEM + wid * 1088;
    const int c = lane & 15;
#pragma unroll
    for (int i = 0; i < 4; ++i) {
#pragma unroll
        for (int j = 0; j < 4; ++j)
#pragma unroll
            for (int r = 0; r < 4; ++r)
                rep[(q * 4 + r) * 68 + j * 16 + c] = acc[i][j][r];
#pragma unroll
        for (int p = 0; p < 4; ++p) {
            int row16 = p * 4 + (lane >> 4);
            int c4 = (lane & 15) * 4;
            float4 v = *(const float4*)&rep[row16 * 68 + c4];
            int grow = row0 + wm + i * 16 + row16;
            if (grow < M) {
                ushort4 o;
                o.x = f2bf(v.x); o.y = f2bf(v.y); o.z = f2bf(v.z); o.w = f2bf(v.w);
                *(ushort4*)(Cb + (size_t)grow * 256 + wn + c4) = o;  // 16 lanes = 128B line
            }
        }
    }

    // fused head dots from fp32 accumulators
    const int head = wid & 3;
    const float* alh = al + head * 64;
    const float* arh = ar + head * 64;
    float a0 = alh[c], a1 = alh[16 + c], a2 = alh[32 + c], a3 = alh[48 + c];
    float r0 = arh[c], r1 = arh[16 + c], r2 = arh[32 + c], r3 = arh[48 + c];
#pragma unroll
    for (int i = 0; i < 4; ++i)
#pragma unroll
        for (int r = 0; r < 4; ++r) {
            float pel = acc[i][0][r] * a0 + acc[i][1][r] * a1 + acc[i][2][r] * a2 + acc[i][3][r] * a3;
            float per = acc[i][0][r] * r0 + acc[i][1][r] * r1 + acc[i][2][r] * r2 + acc[i][3][r] * r3;
#pragma unroll
            for (int off = 8; off >= 1; off >>= 1) {
                pel += __shfl_xor(pel, off);
                per += __shfl_xor(per, off);
            }
            if (c == 0) {
                int grow = row0 + wm + i * 16 + q * 4 + r;
                if (grow < M) {
                    el[(size_t)grow * 4 + head] = pel;
                    er[(size_t)grow * 4 + head] = per;
                }
            }
        }
}

// ---------------- output MFMA GEMM: feat_o[N,64pad] bf16 = h_bf[N,256] @ W_o ----------------
#define LDSK 40
#define BSTRIDE 264
#define OSTR 64   // feat_o row stride (elements): 128B line-aligned
__global__ __launch_bounds__(256) void gemm_out_mfma(const unsigned short* __restrict__ h,
                                                     const unsigned short* __restrict__ Wt,
                                                     const float* __restrict__ alo,
                                                     const float* __restrict__ aro,
                                                     unsigned short* __restrict__ feat_o,
                                                     float* __restrict__ elo,
                                                     float* __restrict__ ero, int N) {
    __shared__ unsigned short As[128 * LDSK];
    __shared__ unsigned short Bs[48 * BSTRIDE];
    const int tid = threadIdx.x;
    const int row0 = blockIdx.x * 128;
    const int lane = tid & 63, wid = tid >> 6;

#pragma unroll
    for (int i = 0; i < 6; ++i) {
        int f = tid + 256 * i;
        int n = f >> 5, kk = (f & 31) * 8;
        *(bf16x8*)&Bs[n * BSTRIDE + kk] = *(const bf16x8*)(Wt + n * 256 + kk);
    }
    __syncthreads();

    floatx4 acc[2][3] = {};
    for (int kb = 0; kb < 256; kb += 32) {
#pragma unroll
        for (int i = 0; i < 2; ++i) {
            int idx = tid + 256 * i;
            int r = idx >> 2, k8 = (idx & 3) * 8;
            int gr = row0 + r;
            bf16x8 v = {};
            if (gr < N) v = *(const bf16x8*)(h + (size_t)gr * 256 + kb + k8);
            *(bf16x8*)&As[r * LDSK + k8] = v;
        }
        __syncthreads();
        const int q = lane >> 4, m = lane & 15;
        bf16x8 af[2], bfr[3];
#pragma unroll
        for (int i = 0; i < 2; ++i)
            af[i] = *(const bf16x8*)&As[(wid * 32 + i * 16 + m) * LDSK + q * 8];
#pragma unroll
        for (int j = 0; j < 3; ++j)
            bfr[j] = *(const bf16x8*)&Bs[(j * 16 + m) * BSTRIDE + kb + q * 8];
#pragma unroll
        for (int i = 0; i < 2; ++i)
#pragma unroll
            for (int j = 0; j < 3; ++j)
                acc[i][j] = __builtin_amdgcn_mfma_f32_16x16x32_bf16(af[i], bfr[j], acc[i][j], 0, 0, 0);
        __syncthreads();
    }

    const int q = lane >> 4, c = lane & 15;
#pragma unroll
    for (int i = 0; i < 2; ++i)
#pragma unroll
        for (int j = 0; j < 3; ++j)
#pragma unroll
            for (int r = 0; r < 4; ++r) {
                int grow = row0 + wid * 32 + i * 16 + q * 4 + r;
                int gcol = j * 16 + c;
                if (grow < N && gcol < 40) feat_o[(size_t)grow * OSTR + gcol] = f2bf(acc[i][j][r]);
            }

    float aj[3], rj[3];
#pragma unroll
    for (int j = 0; j < 3; ++j) {
        int gcol = j * 16 + c;
        aj[j] = gcol < 40 ? alo[gcol] : 0.f;
        rj[j] = gcol < 40 ? aro[gcol] : 0.f;
    }
#pragma unroll
    for (int i = 0; i < 2; ++i)
#pragma unroll
        for (int r = 0; r < 4; ++r) {
            float pl = acc[i][0][r] * aj[0] + acc[i][1][r] * aj[1] + acc[i][2][r] * aj[2];
            float pr = acc[i][0][r] * rj[0] + acc[i][1][r] * rj[1] + acc[i][2][r] * rj[2];
#pragma unroll
            for (int off = 8; off >= 1; off >>= 1) {
                pl += __shfl_xor(pl, off);
                pr += __shfl_xor(pr, off);
            }
            if (c == 0) {
                int grow = row0 + wid * 32 + i * 16 + q * 4 + r;
                if (grow < N) {
                    elo[grow] = pl;
                    ero[grow] = pr;
                }
            }
        }
}

// ---------------- hidden-layer aggregation: single pass + fused epilogue ----------------
__global__ __launch_bounds__(256) void aggregate_hidden(
    const unsigned short* __restrict__ feat, const float* __restrict__ el,
    const float* __restrict__ er, const int* __restrict__ start, const int* __restrict__ endp,
    const int* __restrict__ col, const float* __restrict__ bias, const float* __restrict__ lng,
    const float* __restrict__ lnb, const unsigned short* __restrict__ h_in,
    const float* __restrict__ h_in_f32,
    unsigned short* __restrict__ h_out, int N) {
    int node = blockIdx.x * 4 + (threadIdx.x >> 6);
    int lane = threadIdx.x & 63;
    if (node >= N) return;
    int begin = __builtin_amdgcn_readfirstlane(start[node]);
    int end = __builtin_amdgcn_readfirstlane(endp[node]);
    const int head = lane >> 4;
    const float erh = er[(size_t)node * 4 + head];

    const int ch = lane * 4;
    const unsigned short* fbase = feat + ch;
    const size_t hstr = 256;
    float4 acc = {0.f, 0.f, 0.f, 0.f};
    float ssum = 0.f;
    int e = begin;
    for (; e + 7 < end; e += 8) {
        int sA = col[e], sB = col[e + 1], sC = col[e + 2], sD = col[e + 3];
        int sE = col[e + 4], sF = col[e + 5], sG = col[e + 6], sH = col[e + 7];
        float eA = el[(size_t)sA * 4 + head];
        float eB = el[(size_t)sB * 4 + head];
        float eC = el[(size_t)sC * 4 + head];
        float eD = el[(size_t)sD * 4 + head];
        float eE = el[(size_t)sE * 4 + head];
        float eF = el[(size_t)sF * 4 + head];
        float eG = el[(size_t)sG * 4 + head];
        float eH = el[(size_t)sH * 4 + head];
        ushort4 uA = *(const ushort4*)(fbase + sA * hstr);
        ushort4 uB = *(const ushort4*)(fbase + sB * hstr);
        ushort4 uC = *(const ushort4*)(fbase + sC * hstr);
        ushort4 uD = *(const ushort4*)(fbase + sD * hstr);
        ushort4 uE = *(const ushort4*)(fbase + sE * hstr);
        ushort4 uF = *(const ushort4*)(fbase + sF * hstr);
        ushort4 uG = *(const ushort4*)(fbase + sG * hstr);
        ushort4 uH = *(const ushort4*)(fbase + sH * hstr);
        float wA = __expf(leaky(eA + erh));
        float wB = __expf(leaky(eB + erh));
        float wC = __expf(leaky(eC + erh));
        float wD = __expf(leaky(eD + erh));
        float wE = __expf(leaky(eE + erh));
        float wF = __expf(leaky(eF + erh));
        float wG = __expf(leaky(eG + erh));
        float wH = __expf(leaky(eH + erh));
        ssum += wA + wB + wC + wD + wE + wF + wG + wH;
        acc.x = fmaf(wA, bf2f(uA.x), acc.x); acc.y = fmaf(wA, bf2f(uA.y), acc.y);
        acc.z = fmaf(wA, bf2f(uA.z), acc.z); acc.w = fmaf(wA, bf2f(uA.w), acc.w);
        acc.x = fmaf(wB, bf2f(uB.x), acc.x); acc.y = fmaf(wB, bf2f(uB.y), acc.y);
        acc.z = fmaf(wB, bf2f(uB.z), acc.z); acc.w = fmaf(wB, bf2f(uB.w), acc.w);
        acc.x = fmaf(wC, bf2f(uC.x), acc.x); acc.y = fmaf(wC, bf2f(uC.y), acc.y);
        acc.z = fmaf(wC, bf2f(uC.z), acc.z); acc.w = fmaf(wC, bf2f(uC.w), acc.w);
        acc.x = fmaf(wD, bf2f(uD.x), acc.x); acc.y = fmaf(wD, bf2f(uD.y), acc.y);
        acc.z = fmaf(wD, bf2f(uD.z), acc.z); acc.w = fmaf(wD, bf2f(uD.w), acc.w);
        acc.x = fmaf(wE, bf2f(uE.x), acc.x); acc.y = fmaf(wE, bf2f(uE.y), acc.y);
        acc.z = fmaf(wE, bf2f(uE.z), acc.z); acc.w = fmaf(wE, bf2f(uE.w), acc.w);
        acc.x = fmaf(wF, bf2f(uF.x), acc.x); acc.y = fmaf(wF, bf2f(uF.y), acc.y);
        acc.z = fmaf(wF, bf2f(uF.z), acc.z); acc.w = fmaf(wF, bf2f(uF.w), acc.w);
        acc.x = fmaf(wG, bf2f(uG.x), acc.x); acc.y = fmaf(wG, bf2f(uG.y), acc.y);
        acc.z = fmaf(wG, bf2f(uG.z), acc.z); acc.w = fmaf(wG, bf2f(uG.w), acc.w);
        acc.x = fmaf(wH, bf2f(uH.x), acc.x); acc.y = fmaf(wH, bf2f(uH.y), acc.y);
        acc.z = fmaf(wH, bf2f(uH.z), acc.z); acc.w = fmaf(wH, bf2f(uH.w), acc.w);
    }
    for (; e < end; ++e) {
        int sA = col[e];
        float wA = __expf(leaky(el[(size_t)sA * 4 + head] + erh));
        ushort4 uA = *(const ushort4*)(fbase + sA * hstr);
        ssum += wA;
        acc.x = fmaf(wA, bf2f(uA.x), acc.x); acc.y = fmaf(wA, bf2f(uA.y), acc.y);
        acc.z = fmaf(wA, bf2f(uA.z), acc.z); acc.w = fmaf(wA, bf2f(uA.w), acc.w);
    }
    float inv = ssum > 0.f ? 1.f / ssum : 0.f;
    acc.x *= inv; acc.y *= inv; acc.z *= inv; acc.w *= inv;

    float4 bb = *(const float4*)(bias + ch);
    float x0 = acc.x + bb.x, x1 = acc.y + bb.y, x2 = acc.z + bb.z, x3 = acc.w + bb.w;
    x0 = x0 > 0.f ? x0 : expm1f(x0);
    x1 = x1 > 0.f ? x1 : expm1f(x1);
    x2 = x2 > 0.f ? x2 : expm1f(x2);
    x3 = x3 > 0.f ? x3 : expm1f(x3);
    float lsum = x0 + x1 + x2 + x3;
    float lsq = x0 * x0 + x1 * x1 + x2 * x2 + x3 * x3;
#pragma unroll
    for (int off = 32; off >= 1; off >>= 1) {
        lsum += __shfl_xor(lsum, off);
        lsq += __shfl_xor(lsq, off);
    }
    float mu = lsum * (1.f / 256.f);
    float var = lsq * (1.f / 256.f) - mu * mu;
    float rstd = rsqrtf(var + 1e-5f);
    float4 g4 = *(const float4*)(lng + ch);
    float4 b4 = *(const float4*)(lnb + ch);
    float rx, ry, rz, rw;
    if (h_in_f32) {
        float4 hf = *(const float4*)(h_in_f32 + (size_t)node * 256 + ch);
        rx = hf.x; ry = hf.y; rz = hf.z; rw = hf.w;
    } else {
        ushort4 hi = *(const ushort4*)(h_in + (size_t)node * 256 + ch);
        rx = bf2f(hi.x); ry = bf2f(hi.y); rz = bf2f(hi.z); rw = bf2f(hi.w);
    }
    float y0 = (x0 - mu) * rstd * g4.x + b4.x;
    float y1 = (x1 - mu) * rstd * g4.y + b4.y;
    float y2 = (x2 - mu) * rstd * g4.z + b4.z;
    float y3 = (x3 - mu) * rstd * g4.w + b4.w;
    y0 = (y0 >= 0.f ? y0 : 0.2f * y0) + rx;
    y1 = (y1 >= 0.f ? y1 : 0.2f * y1) + ry;
    y2 = (y2 >= 0.f ? y2 : 0.2f * y2) + rz;
    y3 = (y3 >= 0.f ? y3 : 0.2f * y3) + rw;
    ushort4 o;
    o.x = f2bf(y0); o.y = f2bf(y1); o.z = f2bf(y2); o.w = f2bf(y3);
    *(ushort4*)(h_out + (size_t)node * 256 + ch) = o;
}

// ---------------- output aggregation: logits[N,40], single pass ----------------
__global__ __launch_bounds__(256) void aggregate_out(const unsigned short* __restrict__ feat_o,
                                                     const float* __restrict__ elo,
                                                     const float* __restrict__ ero,
                                                     const int* __restrict__ start,
                                                     const int* __restrict__ endp,
                                                     const int* __restrict__ col,
                                                     const float* __restrict__ bias_o,
                                                     float* __restrict__ out, int N) {
    int node = blockIdx.x * 4 + (threadIdx.x >> 6);
    int lane = threadIdx.x & 63;
    if (node >= N) return;
    int begin = __builtin_amdgcn_readfirstlane(start[node]);
    int end = __builtin_amdgcn_readfirstlane(endp[node]);
    float ern = ero[node];
    int cc = lane < 40 ? lane : 0;
    float acc = 0.f, ssum = 0.f;
    int e = begin;
    for (; e + 7 < end; e += 8) {
        int sA = col[e], sB = col[e + 1], sC = col[e + 2], sD = col[e + 3];
        int sE = col[e + 4], sF = col[e + 5], sG = col[e + 6], sH = col[e + 7];
        float eA = elo[sA], eB = elo[sB], eC = elo[sC], eD = elo[sD];
        float eE = elo[sE], eF = elo[sF], eG = elo[sG], eH = elo[sH];
        unsigned short fA = feat_o[(size_t)sA * OSTR + cc];
        unsigned short fB = feat_o[(size_t)sB * OSTR + cc];
        unsigned short fC = feat_o[(size_t)sC * OSTR + cc];
        unsigned short fD = feat_o[(size_t)sD * OSTR + cc];
        unsigned short fE = feat_o[(size_t)sE * OSTR + cc];
        unsigned short fF = feat_o[(size_t)sF * OSTR + cc];
        unsigned short fG = feat_o[(size_t)sG * OSTR + cc];
        unsigned short fH = feat_o[(size_t)sH * OSTR + cc];
        float wA = __expf(leaky(eA + ern));
        float wB = __expf(leaky(eB + ern));
        float wC = __expf(leaky(eC + ern));
        float wD = __expf(leaky(eD + ern));
        float wE = __expf(leaky(eE + ern));
        float wF = __expf(leaky(eF + ern));
        float wG = __expf(leaky(eG + ern));
        float wH = __expf(leaky(eH + ern));
        ssum += wA + wB + wC + wD + wE + wF + wG + wH;
        acc = fmaf(wA, bf2f(fA), acc);
        acc = fmaf(wB, bf2f(fB), acc);
        acc = fmaf(wC, bf2f(fC), acc);
        acc = fmaf(wD, bf2f(fD), acc);
        acc = fmaf(wE, bf2f(fE), acc);
        acc = fmaf(wF, bf2f(fF), acc);
        acc = fmaf(wG, bf2f(fG), acc);
        acc = fmaf(wH, bf2f(fH), acc);
    }
    for (; e < end; ++e) {
        int sA = col[e];
        float wA = __expf(leaky(elo[sA] + ern));
        ssum += wA;
        acc = fmaf(wA, bf2f(feat_o[(size_t)sA * OSTR + cc]), acc);
    }
    float inv = ssum > 0.f ? 1.f / ssum : 0.f;
    if (lane < 40) out[(size_t)node * 40 + lane] = acc * inv + bias_o[lane];
}

// ---------------- launcher ----------------
extern "C" void kernel_launch(void* const* d_in, const int* in_sizes, int n_in,
                              void* d_out, int out_size, void* d_ws, size_t ws_size,
                              hipStream_t stream) {
    const float* x = (const float*)d_in[0];
    const float* W_h = (const float*)d_in[1];
    const float* al_h = (const float*)d_in[2];
    const float* ar_h = (const float*)d_in[3];
    const float* bias_h = (const float*)d_in[4];
    const float* ln_g = (const float*)d_in[5];
    const float* ln_b = (const float*)d_in[6];
    const float* W_o = (const float*)d_in[7];
    const float* al_o = (const float*)d_in[8];
    const float* ar_o = (const float*)d_in[9];
    const float* bias_o = (const float*)d_in[10];
    const int* esrc = (const int*)d_in[11];
    const int* edst = (const int*)d_in[12];
    const int N = in_sizes[0] / 256;
    const int E = in_sizes[11];
    float* out = (float*)d_out;

    char* ws = (char*)d_ws;
    size_t off = 0;
    auto walloc = [&](size_t bytes) -> void* {
        void* p = ws + off;
        off += (bytes + 255) & ~(size_t)255;
        return p;
    };
    unsigned short* h_bf = (unsigned short*)walloc((size_t)N * 256 * 2);
    unsigned short* feat_bf = (unsigned short*)walloc((size_t)N * 256 * 2);
    unsigned short* Wt = (unsigned short*)walloc((size_t)3 * 65536 * 2);
    unsigned short* Wt_o = (unsigned short*)walloc((size_t)48 * 256 * 2);
    float* el = (float*)walloc((size_t)N * 4 * 4);
    float* er = (float*)walloc((size_t)N * 4 * 4);
    int* start = (int*)walloc((size_t)N * 4);
    int* endp = (int*)walloc((size_t)N * 4);
    int* col = (int*)walloc((size_t)E * 4);
    int* bcnt = (int*)walloc(1024 * 4);
    int* bbase = (int*)walloc(1024 * 4);
    int* bcursor = (int*)walloc(1024 * 4);
    int2* pairs = (int2*)walloc((size_t)E * 8);
    if (off > ws_size) return;

    const int TB = 256;
    const int nbkt = (N + 127) >> 7;            // 128 nodes per bucket
    const int nbe = (E + 8191) / 8192;
    transpose_all<<<(3 * 65536 + 48 * 256) / TB, TB, 0, stream>>>(W_h, Wt, W_o, Wt_o);
    hipMemsetAsync(bcnt, 0, (size_t)nbkt * 4, stream);
    bucket_count<<<nbe, TB, 0, stream>>>(edst, bcnt, E, nbkt);
    bucket_scan<<<1, TB, 0, stream>>>(bcnt, bbase, bcursor, nbkt);
    bucket_partition<<<nbe, TB, 0, stream>>>(esrc, edst, bcursor, pairs, E, nbkt);
    csr_bucket<<<nbkt, TB, 0, stream>>>(pairs, bbase, start, endp, col, N, E, nbkt);

    const int nb4 = (N + 3) / 4;
    const int gemm_grid = (N + 127) / 128;
    for (int l = 0; l < 3; ++l) {
        if (l == 0) {
            gemm_fused<true><<<gemm_grid, 512, 0, stream>>>(x, Wt, al_h, ar_h,
                                                            feat_bf, el, er, N);
        } else {
            gemm_fused<false><<<gemm_grid, 512, 0, stream>>>(h_bf, Wt + (size_t)l * 65536,
                                                             al_h + l * 256, ar_h + l * 256,
                                                             feat_bf, el, er, N);
        }
        const unsigned short* hin_bf = h_bf;
        const float* hin_f32 = (l == 0) ? x : nullptr;
        aggregate_hidden<<<nb4, 256, 0, stream>>>(feat_bf, el, er, start, endp, col,
                                                  bias_h + l * 256, ln_g + l * 256,
                                                  ln_b + l * 256, hin_bf, hin_f32, h_bf, N);
    }
    unsigned short* feat_o = feat_bf;  // reuse; OSTR=64 rows fit in 256-wide buffer
    float* elo = el;
    float* ero = er;
    gemm_out_mfma<<<(N + 127) / 128, 256, 0, stream>>>(h_bf, Wt_o, al_o, ar_o, feat_o, elo, ero, N);
    aggregate_out<<<nb4, 256, 0, stream>>>(feat_o, elo, ero, start, endp, col, bias_o, out, N);
}

// Round 10
// 856.123 us; speedup vs baseline: 1.1725x; 1.0107x over previous
//
#include <hip/hip_runtime.h>
#include <math.h>

// GAT: 3 hidden GATConv layers (H=4, D=64, HID=256) + LN + leaky + residual,
// then output GATConv (H=1, C=40). N=100000 nodes, E=1600000 edges.
//
// Round 19: counted-vmcnt GEMM pipeline. The per-K-iter __syncthreads()
// drains vmcnt(0) including the JUST-ISSUED next-tile prefetch -> every
// iter pays a full HBM round-trip (fill/drain dominated at K=256/8 iters).
// Replaced with s_waitcnt vmcnt(3) (waits only the PREVIOUS stage's 3
// gl_lds per wave) + raw s_barrier + sched_barrier(0) pinning; prefetch
// stays in flight across the barrier under the MFMA compute (AITER/T4
// pattern). F32 path: vmcnt(2)+lgkmcnt(0) (2 gl_lds + A ds_write).
// aggregate_hidden confirmed at 97% of device BW (6.1/6.29 TB/s) - done.
// Everything else unchanged from R18 (865us).

#define NEG_SLOPE 0.2f

typedef __attribute__((ext_vector_type(8))) short bf16x8;
typedef __attribute__((ext_vector_type(4))) float floatx4;

__device__ __forceinline__ float leaky(float x) { return x >= 0.f ? x : NEG_SLOPE * x; }

__device__ __forceinline__ unsigned short f2bf(float f) {
    unsigned u = __builtin_bit_cast(unsigned, f);
    u += 0x7fffu + ((u >> 16) & 1u);  // RNE
    return (unsigned short)(u >> 16);
}
__device__ __forceinline__ float bf2f(unsigned short h) {
    unsigned u = ((unsigned)h) << 16;
    return __builtin_bit_cast(float, u);
}

// async global->LDS, 16B per lane (global_load_lds_dwordx4)
typedef const __attribute__((address_space(1))) unsigned int* as1_u32p;
typedef __attribute__((address_space(3))) unsigned int* as3_u32p;
__device__ __forceinline__ void gl_lds16(const void* g, void* l) {
    __builtin_amdgcn_global_load_lds((as1_u32p)g, (as3_u32p)l, 16, 0, 0);
}

// ---------------- bucketed CSR build ----------------
__global__ __launch_bounds__(256) void bucket_count(const int* __restrict__ dst,
                                                    int* __restrict__ bcnt, int E, int nbkt) {
    __shared__ int h[1024];
    for (int i = threadIdx.x; i < nbkt; i += 256) h[i] = 0;
    __syncthreads();
    const int base = blockIdx.x * 8192;
#pragma unroll 4
    for (int i = 0; i < 32; ++i) {
        int e = base + threadIdx.x + i * 256;
        if (e < E) atomicAdd(&h[dst[e] >> 7], 1);
    }
    __syncthreads();
    for (int i = threadIdx.x; i < nbkt; i += 256) {
        int v = h[i];
        if (v) atomicAdd(&bcnt[i], v);
    }
}

__global__ __launch_bounds__(256) void bucket_scan(const int* __restrict__ bcnt,
                                                   int* __restrict__ bbase,
                                                   int* __restrict__ bcursor, int nbkt) {
    __shared__ int s[256];
    const int t = threadIdx.x;
    int c[4];
    int tsum = 0;
#pragma unroll
    for (int j = 0; j < 4; ++j) {
        int i = t * 4 + j;
        c[j] = (i < nbkt) ? bcnt[i] : 0;
        tsum += c[j];
    }
    s[t] = tsum;
    __syncthreads();
    for (int off = 1; off < 256; off <<= 1) {
        int v = (t >= off) ? s[t - off] : 0;
        __syncthreads();
        s[t] += v;
        __syncthreads();
    }
    int excl = s[t] - tsum;
#pragma unroll
    for (int j = 0; j < 4; ++j) {
        int i = t * 4 + j;
        if (i < nbkt) {
            bbase[i] = excl;
            bcursor[i] = excl;
        }
        excl += c[j];
    }
}

__global__ __launch_bounds__(256) void bucket_partition(const int* __restrict__ src,
                                                        const int* __restrict__ dst,
                                                        int* __restrict__ bcursor,
                                                        int2* __restrict__ pairs, int E, int nbkt) {
    __shared__ int h[1024];
    __shared__ int basech[1024];
    for (int i = threadIdx.x; i < nbkt; i += 256) h[i] = 0;
    __syncthreads();
    const int base = blockIdx.x * 8192;
#pragma unroll 4
    for (int i = 0; i < 32; ++i) {
        int e = base + threadIdx.x + i * 256;
        if (e < E) atomicAdd(&h[dst[e] >> 7], 1);
    }
    __syncthreads();
    for (int i = threadIdx.x; i < nbkt; i += 256) {
        int v = h[i];
        basech[i] = v ? atomicAdd(&bcursor[i], v) : 0;
    }
    __syncthreads();
    for (int i = threadIdx.x; i < nbkt; i += 256) h[i] = 0;
    __syncthreads();
#pragma unroll 4
    for (int i = 0; i < 32; ++i) {
        int e = base + threadIdx.x + i * 256;
        if (e < E) {
            int d = dst[e], b = d >> 7;
            int r = atomicAdd(&h[b], 1);
            pairs[basech[b] + r] = make_int2(src[e], d);
        }
    }
}

__global__ __launch_bounds__(256) void csr_bucket(const int2* __restrict__ pairs,
                                                  const int* __restrict__ bbase,
                                                  int* __restrict__ start, int* __restrict__ endp,
                                                  int* __restrict__ col, int N, int E, int nbkt) {
    const int b = blockIdx.x;
    const int node0 = b << 7;
    int nc = N - node0;
    if (nc <= 0) return;
    if (nc > 128) nc = 128;
    __shared__ int cnt[128];
    __shared__ int s[128];
    const int t = threadIdx.x;
    if (t < 128) cnt[t] = 0;
    __syncthreads();
    const int ebase = bbase[b];
    const int eend = (b + 1 < nbkt) ? bbase[b + 1] : E;
    for (int e = ebase + t; e < eend; e += 256) {
        atomicAdd(&cnt[pairs[e].y - node0], 1);
    }
    __syncthreads();
    if (t < 128) s[t] = cnt[t];
    __syncthreads();
    for (int off = 1; off < 128; off <<= 1) {
        int v = 0;
        if (t < 128 && t >= off) v = s[t - off];
        __syncthreads();
        if (t < 128) s[t] += v;
        __syncthreads();
    }
    if (t < nc) {
        start[node0 + t] = ebase + s[t] - cnt[t];
        endp[node0 + t] = ebase + s[t];
    }
    if (t < 128) cnt[t] = s[t] - cnt[t];  // -> exclusive cursor
    __syncthreads();
    for (int e = ebase + t; e < eend; e += 256) {
        int2 pr = pairs[e];
        int r = atomicAdd(&cnt[pr.y - node0], 1);
        col[ebase + r] = pr.x;
    }
}

// ---------------- weight pre-transpose (merged): Wt + Wt_o ----------------
__global__ void transpose_all(const float* __restrict__ W, unsigned short* __restrict__ Wt,
                              const float* __restrict__ Wo, unsigned short* __restrict__ Wt_o) {
    int idx = blockIdx.x * 256 + threadIdx.x;
    if (idx < 3 * 65536) {
        int l = idx >> 16, r = idx & 65535;
        int k = r >> 8, n = r & 255;
        Wt[l * 65536 + n * 256 + k] = f2bf(W[l * 65536 + k * 256 + n]);
    } else {
        int j = idx - 3 * 65536;           // 48*256 entries
        int n = j >> 8, k = j & 255;
        Wt_o[n * 256 + k] = (n < 40) ? f2bf(Wo[k * 40 + n]) : (unsigned short)0;
    }
}

// ---------------- staged MFMA GEMM, counted-vmcnt pipeline + coalesced epilogue ----
template <bool F32>
__global__ __launch_bounds__(512, 4) void gemm_fused(
    const void* __restrict__ Av, const unsigned short* __restrict__ Wt,
    const float* __restrict__ al, const float* __restrict__ ar,
    unsigned short* __restrict__ Cb, float* __restrict__ el, float* __restrict__ er, int M) {
    const unsigned short* Ab = (const unsigned short*)Av;
    const float* Af = (const float*)Av;
    __shared__ unsigned short SMEM[24576];          // 48KB: staging, then repack
    unsigned short* As = SMEM;                      // [2][128*32]
    unsigned short* Bs = SMEM + 2 * 128 * 32;       // [2][256*32]
    const int tid = threadIdx.x;
    const int row0 = blockIdx.x * 128;
    const int lane = tid & 63, wid = tid >> 6;
    const int wm = (wid >> 2) * 64;   // 0 or 64
    const int wn = (wid & 3) * 64;    // 0,64,128,192
    const int q = lane >> 4, m = lane & 15;

    const int arow = wid * 16 + (lane >> 2);
    const int brow0 = wid * 32 + (lane >> 2);
    const int kx = (lane & 3) * 8;
    const int agr = (row0 + arow < M) ? (row0 + arow) : (M - 1);

    auto stage = [&](int buf, int kb) {
        if constexpr (F32) {
            const float* p = Af + (size_t)agr * 256 + kb + kx;
            float4 f0 = *(const float4*)p;
            float4 f1 = *(const float4*)(p + 4);
            bf16x8 v;
            v[0] = (short)f2bf(f0.x); v[1] = (short)f2bf(f0.y);
            v[2] = (short)f2bf(f0.z); v[3] = (short)f2bf(f0.w);
            v[4] = (short)f2bf(f1.x); v[5] = (short)f2bf(f1.y);
            v[6] = (short)f2bf(f1.z); v[7] = (short)f2bf(f1.w);
            *(bf16x8*)&As[buf * 128 * 32 + arow * 32 + kx] = v;
        } else {
            gl_lds16(Ab + (size_t)agr * 256 + kb + kx, &As[buf * 128 * 32 + arow * 32 + kx]);
        }
        gl_lds16(Wt + (size_t)brow0 * 256 + kb + kx, &Bs[buf * 256 * 32 + brow0 * 32 + kx]);
        gl_lds16(Wt + (size_t)(brow0 + 16) * 256 + kb + kx,
                 &Bs[buf * 256 * 32 + (brow0 + 16) * 32 + kx]);
    };

    floatx4 acc[4][4] = {};
    stage(0, 0);
    int cur = 0;
    for (int kb = 0; kb < 256; kb += 32) {
        int nkb = kb + 32;
        if (nkb < 256) stage(cur ^ 1, nkb);   // prefetch stays in flight across barrier
        // barrier1: wait only for stage(cur)'s own loads (counted), then sync.
        if (nkb < 256) {
            if constexpr (F32) {
                asm volatile("s_waitcnt vmcnt(2) lgkmcnt(0)" ::: "memory");
            } else {
                asm volatile("s_waitcnt vmcnt(3)" ::: "memory");
            }
        } else {
            asm volatile("s_waitcnt vmcnt(0) lgkmcnt(0)" ::: "memory");
        }
        __builtin_amdgcn_s_barrier();
        __builtin_amdgcn_sched_barrier(0);    // pin: no ds_read hoisted above barrier
        bf16x8 af[4], bfr[4];
#pragma unroll
        for (int i = 0; i < 4; ++i) {
            af[i] = *(const bf16x8*)&As[cur * 128 * 32 + (wm + i * 16 + m) * 32 + q * 8];
            bfr[i] = *(const bf16x8*)&Bs[cur * 256 * 32 + (wn + i * 16 + m) * 32 + q * 8];
        }
#pragma unroll
        for (int i = 0; i < 4; ++i)
#pragma unroll
            for (int j = 0; j < 4; ++j)
                acc[i][j] = __builtin_amdgcn_mfma_f32_16x16x32_bf16(af[i], bfr[j], acc[i][j], 0, 0, 0);
        // barrier2: all waves done reading buf cur before next iter overwrites it.
        __builtin_amdgcn_sched_barrier(0);
        __builtin_amdgcn_s_barrier();
        __builtin_amdgcn_sched_barrier(0);
        cur ^= 1;
    }
    // reuse staging LDS as wave-private repack scratch: [16][68] fp32 per wave
    float* rep = (float*)SMEM + wid * 1088;
    const int c = lane & 15;
#pragma unroll
    for (int i = 0; i < 4; ++i) {
#pragma unroll
        for (int j = 0; j < 4; ++j)
#pragma unroll
            for (int r = 0; r < 4; ++r)
                rep[(q * 4 + r) * 68 + j * 16 + c] = acc[i][j][r];
#pragma unroll
        for (int p = 0; p < 4; ++p) {
            int row16 = p * 4 + (lane >> 4);
            int c4 = (lane & 15) * 4;
            float4 v = *(const float4*)&rep[row16 * 68 + c4];
            int grow = row0 + wm + i * 16 + row16;
            if (grow < M) {
                ushort4 o;
                o.x = f2bf(v.x); o.y = f2bf(v.y); o.z = f2bf(v.z); o.w = f2bf(v.w);
                *(ushort4*)(Cb + (size_t)grow * 256 + wn + c4) = o;  // 16 lanes = 128B line
            }
        }
    }

    // fused head dots from fp32 accumulators
    const int head = wid & 3;
    const float* alh = al + head * 64;
    const float* arh = ar + head * 64;
    float a0 = alh[c], a1 = alh[16 + c], a2 = alh[32 + c], a3 = alh[48 + c];
    float r0 = arh[c], r1 = arh[16 + c], r2 = arh[32 + c], r3 = arh[48 + c];
#pragma unroll
    for (int i = 0; i < 4; ++i)
#pragma unroll
        for (int r = 0; r < 4; ++r) {
            float pel = acc[i][0][r] * a0 + acc[i][1][r] * a1 + acc[i][2][r] * a2 + acc[i][3][r] * a3;
            float per = acc[i][0][r] * r0 + acc[i][1][r] * r1 + acc[i][2][r] * r2 + acc[i][3][r] * r3;
#pragma unroll
            for (int off = 8; off >= 1; off >>= 1) {
                pel += __shfl_xor(pel, off);
                per += __shfl_xor(per, off);
            }
            if (c == 0) {
                int grow = row0 + wm + i * 16 + q * 4 + r;
                if (grow < M) {
                    el[(size_t)grow * 4 + head] = pel;
                    er[(size_t)grow * 4 + head] = per;
                }
            }
        }
}

// ---------------- output MFMA GEMM: feat_o[N,64pad] bf16 = h_bf[N,256] @ W_o ----------------
#define LDSK 40
#define BSTRIDE 264
#define OSTR 64   // feat_o row stride (elements): 128B line-aligned
__global__ __launch_bounds__(256) void gemm_out_mfma(const unsigned short* __restrict__ h,
                                                     const unsigned short* __restrict__ Wt,
                                                     const float* __restrict__ alo,
                                                     const float* __restrict__ aro,
                                                     unsigned short* __restrict__ feat_o,
                                                     float* __restrict__ elo,
                                                     float* __restrict__ ero, int N) {
    __shared__ unsigned short As[128 * LDSK];
    __shared__ unsigned short Bs[48 * BSTRIDE];
    const int tid = threadIdx.x;
    const int row0 = blockIdx.x * 128;
    const int lane = tid & 63, wid = tid >> 6;

#pragma unroll
    for (int i = 0; i < 6; ++i) {
        int f = tid + 256 * i;
        int n = f >> 5, kk = (f & 31) * 8;
        *(bf16x8*)&Bs[n * BSTRIDE + kk] = *(const bf16x8*)(Wt + n * 256 + kk);
    }
    __syncthreads();

    floatx4 acc[2][3] = {};
    for (int kb = 0; kb < 256; kb += 32) {
#pragma unroll
        for (int i = 0; i < 2; ++i) {
            int idx = tid + 256 * i;
            int r = idx >> 2, k8 = (idx & 3) * 8;
            int gr = row0 + r;
            bf16x8 v = {};
            if (gr < N) v = *(const bf16x8*)(h + (size_t)gr * 256 + kb + k8);
            *(bf16x8*)&As[r * LDSK + k8] = v;
        }
        __syncthreads();
        const int q = lane >> 4, m = lane & 15;
        bf16x8 af[2], bfr[3];
#pragma unroll
        for (int i = 0; i < 2; ++i)
            af[i] = *(const bf16x8*)&As[(wid * 32 + i * 16 + m) * LDSK + q * 8];
#pragma unroll
        for (int j = 0; j < 3; ++j)
            bfr[j] = *(const bf16x8*)&Bs[(j * 16 + m) * BSTRIDE + kb + q * 8];
#pragma unroll
        for (int i = 0; i < 2; ++i)
#pragma unroll
            for (int j = 0; j < 3; ++j)
                acc[i][j] = __builtin_amdgcn_mfma_f32_16x16x32_bf16(af[i], bfr[j], acc[i][j], 0, 0, 0);
        __syncthreads();
    }

    const int q = lane >> 4, c = lane & 15;
#pragma unroll
    for (int i = 0; i < 2; ++i)
#pragma unroll
        for (int j = 0; j < 3; ++j)
#pragma unroll
            for (int r = 0; r < 4; ++r) {
                int grow = row0 + wid * 32 + i * 16 + q * 4 + r;
                int gcol = j * 16 + c;
                if (grow < N && gcol < 40) feat_o[(size_t)grow * OSTR + gcol] = f2bf(acc[i][j][r]);
            }

    float aj[3], rj[3];
#pragma unroll
    for (int j = 0; j < 3; ++j) {
        int gcol = j * 16 + c;
        aj[j] = gcol < 40 ? alo[gcol] : 0.f;
        rj[j] = gcol < 40 ? aro[gcol] : 0.f;
    }
#pragma unroll
    for (int i = 0; i < 2; ++i)
#pragma unroll
        for (int r = 0; r < 4; ++r) {
            float pl = acc[i][0][r] * aj[0] + acc[i][1][r] * aj[1] + acc[i][2][r] * aj[2];
            float pr = acc[i][0][r] * rj[0] + acc[i][1][r] * rj[1] + acc[i][2][r] * rj[2];
#pragma unroll
            for (int off = 8; off >= 1; off >>= 1) {
                pl += __shfl_xor(pl, off);
                pr += __shfl_xor(pr, off);
            }
            if (c == 0) {
                int grow = row0 + wid * 32 + i * 16 + q * 4 + r;
                if (grow < N) {
                    elo[grow] = pl;
                    ero[grow] = pr;
                }
            }
        }
}

// ---------------- hidden-layer aggregation: single pass + fused epilogue ----------------
__global__ __launch_bounds__(256) void aggregate_hidden(
    const unsigned short* __restrict__ feat, const float* __restrict__ el,
    const float* __restrict__ er, const int* __restrict__ start, const int* __restrict__ endp,
    const int* __restrict__ col, const float* __restrict__ bias, const float* __restrict__ lng,
    const float* __restrict__ lnb, const unsigned short* __restrict__ h_in,
    const float* __restrict__ h_in_f32,
    unsigned short* __restrict__ h_out, int N) {
    int node = blockIdx.x * 4 + (threadIdx.x >> 6);
    int lane = threadIdx.x & 63;
    if (node >= N) return;
    int begin = __builtin_amdgcn_readfirstlane(start[node]);
    int end = __builtin_amdgcn_readfirstlane(endp[node]);
    const int head = lane >> 4;
    const float erh = er[(size_t)node * 4 + head];

    const int ch = lane * 4;
    const unsigned short* fbase = feat + ch;
    const size_t hstr = 256;
    float4 acc = {0.f, 0.f, 0.f, 0.f};
    float ssum = 0.f;
    int e = begin;
    for (; e + 7 < end; e += 8) {
        int sA = col[e], sB = col[e + 1], sC = col[e + 2], sD = col[e + 3];
        int sE = col[e + 4], sF = col[e + 5], sG = col[e + 6], sH = col[e + 7];
        float eA = el[(size_t)sA * 4 + head];
        float eB = el[(size_t)sB * 4 + head];
        float eC = el[(size_t)sC * 4 + head];
        float eD = el[(size_t)sD * 4 + head];
        float eE = el[(size_t)sE * 4 + head];
        float eF = el[(size_t)sF * 4 + head];
        float eG = el[(size_t)sG * 4 + head];
        float eH = el[(size_t)sH * 4 + head];
        ushort4 uA = *(const ushort4*)(fbase + sA * hstr);
        ushort4 uB = *(const ushort4*)(fbase + sB * hstr);
        ushort4 uC = *(const ushort4*)(fbase + sC * hstr);
        ushort4 uD = *(const ushort4*)(fbase + sD * hstr);
        ushort4 uE = *(const ushort4*)(fbase + sE * hstr);
        ushort4 uF = *(const ushort4*)(fbase + sF * hstr);
        ushort4 uG = *(const ushort4*)(fbase + sG * hstr);
        ushort4 uH = *(const ushort4*)(fbase + sH * hstr);
        float wA = __expf(leaky(eA + erh));
        float wB = __expf(leaky(eB + erh));
        float wC = __expf(leaky(eC + erh));
        float wD = __expf(leaky(eD + erh));
        float wE = __expf(leaky(eE + erh));
        float wF = __expf(leaky(eF + erh));
        float wG = __expf(leaky(eG + erh));
        float wH = __expf(leaky(eH + erh));
        ssum += wA + wB + wC + wD + wE + wF + wG + wH;
        acc.x = fmaf(wA, bf2f(uA.x), acc.x); acc.y = fmaf(wA, bf2f(uA.y), acc.y);
        acc.z = fmaf(wA, bf2f(uA.z), acc.z); acc.w = fmaf(wA, bf2f(uA.w), acc.w);
        acc.x = fmaf(wB, bf2f(uB.x), acc.x); acc.y = fmaf(wB, bf2f(uB.y), acc.y);
        acc.z = fmaf(wB, bf2f(uB.z), acc.z); acc.w = fmaf(wB, bf2f(uB.w), acc.w);
        acc.x = fmaf(wC, bf2f(uC.x), acc.x); acc.y = fmaf(wC, bf2f(uC.y), acc.y);
        acc.z = fmaf(wC, bf2f(uC.z), acc.z); acc.w = fmaf(wC, bf2f(uC.w), acc.w);
        acc.x = fmaf(wD, bf2f(uD.x), acc.x); acc.y = fmaf(wD, bf2f(uD.y), acc.y);
        acc.z = fmaf(wD, bf2f(uD.z), acc.z); acc.w = fmaf(wD, bf2f(uD.w), acc.w);
        acc.x = fmaf(wE, bf2f(uE.x), acc.x); acc.y = fmaf(wE, bf2f(uE.y), acc.y);
        acc.z = fmaf(wE, bf2f(uE.z), acc.z); acc.w = fmaf(wE, bf2f(uE.w), acc.w);
        acc.x = fmaf(wF, bf2f(uF.x), acc.x); acc.y = fmaf(wF, bf2f(uF.y), acc.y);
        acc.z = fmaf(wF, bf2f(uF.z), acc.z); acc.w = fmaf(wF, bf2f(uF.w), acc.w);
        acc.x = fmaf(wG, bf2f(uG.x), acc.x); acc.y = fmaf(wG, bf2f(uG.y), acc.y);
        acc.z = fmaf(wG, bf2f(uG.z), acc.z); acc.w = fmaf(wG, bf2f(uG.w), acc.w);
        acc.x = fmaf(wH, bf2f(uH.x), acc.x); acc.y = fmaf(wH, bf2f(uH.y), acc.y);
        acc.z = fmaf(wH, bf2f(uH.z), acc.z); acc.w = fmaf(wH, bf2f(uH.w), acc.w);
    }
    for (; e < end; ++e) {
        int sA = col[e];
        float wA = __expf(leaky(el[(size_t)sA * 4 + head] + erh));
        ushort4 uA = *(const ushort4*)(fbase + sA * hstr);
        ssum += wA;
        acc.x = fmaf(wA, bf2f(uA.x), acc.x); acc.y = fmaf(wA, bf2f(uA.y), acc.y);
        acc.z = fmaf(wA, bf2f(uA.z), acc.z); acc.w = fmaf(wA, bf2f(uA.w), acc.w);
    }
    float inv = ssum > 0.f ? 1.f / ssum : 0.f;
    acc.x *= inv; acc.y *= inv; acc.z *= inv; acc.w *= inv;

    float4 bb = *(const float4*)(bias + ch);
    float x0 = acc.x + bb.x, x1 = acc.y + bb.y, x2 = acc.z + bb.z, x3 = acc.w + bb.w;
    x0 = x0 > 0.f ? x0 : expm1f(x0);
    x1 = x1 > 0.f ? x1 : expm1f(x1);
    x2 = x2 > 0.f ? x2 : expm1f(x2);
    x3 = x3 > 0.f ? x3 : expm1f(x3);
    float lsum = x0 + x1 + x2 + x3;
    float lsq = x0 * x0 + x1 * x1 + x2 * x2 + x3 * x3;
#pragma unroll
    for (int off = 32; off >= 1; off >>= 1) {
        lsum += __shfl_xor(lsum, off);
        lsq += __shfl_xor(lsq, off);
    }
    float mu = lsum * (1.f / 256.f);
    float var = lsq * (1.f / 256.f) - mu * mu;
    float rstd = rsqrtf(var + 1e-5f);
    float4 g4 = *(const float4*)(lng + ch);
    float4 b4 = *(const float4*)(lnb + ch);
    float rx, ry, rz, rw;
    if (h_in_f32) {
        float4 hf = *(const float4*)(h_in_f32 + (size_t)node * 256 + ch);
        rx = hf.x; ry = hf.y; rz = hf.z; rw = hf.w;
    } else {
        ushort4 hi = *(const ushort4*)(h_in + (size_t)node * 256 + ch);
        rx = bf2f(hi.x); ry = bf2f(hi.y); rz = bf2f(hi.z); rw = bf2f(hi.w);
    }
    float y0 = (x0 - mu) * rstd * g4.x + b4.x;
    float y1 = (x1 - mu) * rstd * g4.y + b4.y;
    float y2 = (x2 - mu) * rstd * g4.z + b4.z;
    float y3 = (x3 - mu) * rstd * g4.w + b4.w;
    y0 = (y0 >= 0.f ? y0 : 0.2f * y0) + rx;
    y1 = (y1 >= 0.f ? y1 : 0.2f * y1) + ry;
    y2 = (y2 >= 0.f ? y2 : 0.2f * y2) + rz;
    y3 = (y3 >= 0.f ? y3 : 0.2f * y3) + rw;
    ushort4 o;
    o.x = f2bf(y0); o.y = f2bf(y1); o.z = f2bf(y2); o.w = f2bf(y3);
    *(ushort4*)(h_out + (size_t)node * 256 + ch) = o;
}

// ---------------- output aggregation: logits[N,40], single pass ----------------
__global__ __launch_bounds__(256) void aggregate_out(const unsigned short* __restrict__ feat_o,
                                                     const float* __restrict__ elo,
                                                     const float* __restrict__ ero,
                                                     const int* __restrict__ start,
                                                     const int* __restrict__ endp,
                                                     const int* __restrict__ col,
                                                     const float* __restrict__ bias_o,
                                                     float* __restrict__ out, int N) {
    int node = blockIdx.x * 4 + (threadIdx.x >> 6);
    int lane = threadIdx.x & 63;
    if (node >= N) return;
    int begin = __builtin_amdgcn_readfirstlane(start[node]);
    int end = __builtin_amdgcn_readfirstlane(endp[node]);
    float ern = ero[node];
    int cc = lane < 40 ? lane : 0;
    float acc = 0.f, ssum = 0.f;
    int e = begin;
    for (; e + 7 < end; e += 8) {
        int sA = col[e], sB = col[e + 1], sC = col[e + 2], sD = col[e + 3];
        int sE = col[e + 4], sF = col[e + 5], sG = col[e + 6], sH = col[e + 7];
        float eA = elo[sA], eB = elo[sB], eC = elo[sC], eD = elo[sD];
        float eE = elo[sE], eF = elo[sF], eG = elo[sG], eH = elo[sH];
        unsigned short fA = feat_o[(size_t)sA * OSTR + cc];
        unsigned short fB = feat_o[(size_t)sB * OSTR + cc];
        unsigned short fC = feat_o[(size_t)sC * OSTR + cc];
        unsigned short fD = feat_o[(size_t)sD * OSTR + cc];
        unsigned short fE = feat_o[(size_t)sE * OSTR + cc];
        unsigned short fF = feat_o[(size_t)sF * OSTR + cc];
        unsigned short fG = feat_o[(size_t)sG * OSTR + cc];
        unsigned short fH = feat_o[(size_t)sH * OSTR + cc];
        float wA = __expf(leaky(eA + ern));
        float wB = __expf(leaky(eB + ern));
        float wC = __expf(leaky(eC + ern));
        float wD = __expf(leaky(eD + ern));
        float wE = __expf(leaky(eE + ern));
        float wF = __expf(leaky(eF + ern));
        float wG = __expf(leaky(eG + ern));
        float wH = __expf(leaky(eH + ern));
        ssum += wA + wB + wC + wD + wE + wF + wG + wH;
        acc = fmaf(wA, bf2f(fA), acc);
        acc = fmaf(wB, bf2f(fB), acc);
        acc = fmaf(wC, bf2f(fC), acc);
        acc = fmaf(wD, bf2f(fD), acc);
        acc = fmaf(wE, bf2f(fE), acc);
        acc = fmaf(wF, bf2f(fF), acc);
        acc = fmaf(wG, bf2f(fG), acc);
        acc = fmaf(wH, bf2f(fH), acc);
    }
    for (; e < end; ++e) {
        int sA = col[e];
        float wA = __expf(leaky(elo[sA] + ern));
        ssum += wA;
        acc = fmaf(wA, bf2f(feat_o[(size_t)sA * OSTR + cc]), acc);
    }
    float inv = ssum > 0.f ? 1.f / ssum : 0.f;
    if (lane < 40) out[(size_t)node * 40 + lane] = acc * inv + bias_o[lane];
}

// ---------------- launcher ----------------
extern "C" void kernel_launch(void* const* d_in, const int* in_sizes, int n_in,
                              void* d_out, int out_size, void* d_ws, size_t ws_size,
                              hipStream_t stream) {
    const float* x = (const float*)d_in[0];
    const float* W_h = (const float*)d_in[1];
    const float* al_h = (const float*)d_in[2];
    const float* ar_h = (const float*)d_in[3];
    const float* bias_h = (const float*)d_in[4];
    const float* ln_g = (const float*)d_in[5];
    const float* ln_b = (const float*)d_in[6];
    const float* W_o = (const float*)d_in[7];
    const float* al_o = (const float*)d_in[8];
    const float* ar_o = (const float*)d_in[9];
    const float* bias_o = (const float*)d_in[10];
    const int* esrc = (const int*)d_in[11];
    const int* edst = (const int*)d_in[12];
    const int N = in_sizes[0] / 256;
    const int E = in_sizes[11];
    float* out = (float*)d_out;

    char* ws = (char*)d_ws;
    size_t off = 0;
    auto walloc = [&](size_t bytes) -> void* {
        void* p = ws + off;
        off += (bytes + 255) & ~(size_t)255;
        return p;
    };
    unsigned short* h_bf = (unsigned short*)walloc((size_t)N * 256 * 2);
    unsigned short* feat_bf = (unsigned short*)walloc((size_t)N * 256 * 2);
    unsigned short* Wt = (unsigned short*)walloc((size_t)3 * 65536 * 2);
    unsigned short* Wt_o = (unsigned short*)walloc((size_t)48 * 256 * 2);
    float* el = (float*)walloc((size_t)N * 4 * 4);
    float* er = (float*)walloc((size_t)N * 4 * 4);
    int* start = (int*)walloc((size_t)N * 4);
    int* endp = (int*)walloc((size_t)N * 4);
    int* col = (int*)walloc((size_t)E * 4);
    int* bcnt = (int*)walloc(1024 * 4);
    int* bbase = (int*)walloc(1024 * 4);
    int* bcursor = (int*)walloc(1024 * 4);
    int2* pairs = (int2*)walloc((size_t)E * 8);
    if (off > ws_size) return;

    const int TB = 256;
    const int nbkt = (N + 127) >> 7;            // 128 nodes per bucket
    const int nbe = (E + 8191) / 8192;
    transpose_all<<<(3 * 65536 + 48 * 256) / TB, TB, 0, stream>>>(W_h, Wt, W_o, Wt_o);
    hipMemsetAsync(bcnt, 0, (size_t)nbkt * 4, stream);
    bucket_count<<<nbe, TB, 0, stream>>>(edst, bcnt, E, nbkt);
    bucket_scan<<<1, TB, 0, stream>>>(bcnt, bbase, bcursor, nbkt);
    bucket_partition<<<nbe, TB, 0, stream>>>(esrc, edst, bcursor, pairs, E, nbkt);
    csr_bucket<<<nbkt, TB, 0, stream>>>(pairs, bbase, start, endp, col, N, E, nbkt);

    const int nb4 = (N + 3) / 4;
    const int gemm_grid = (N + 127) / 128;
    for (int l = 0; l < 3; ++l) {
        if (l == 0) {
            gemm_fused<true><<<gemm_grid, 512, 0, stream>>>(x, Wt, al_h, ar_h,
                                                            feat_bf, el, er, N);
        } else {
            gemm_fused<false><<<gemm_grid, 512, 0, stream>>>(h_bf, Wt + (size_t)l * 65536,
                                                             al_h + l * 256, ar_h + l * 256,
                                                             feat_bf, el, er, N);
        }
        const unsigned short* hin_bf = h_bf;
        const float* hin_f32 = (l == 0) ? x : nullptr;
        aggregate_hidden<<<nb4, 256, 0, stream>>>(feat_bf, el, er, start, endp, col,
                                                  bias_h + l * 256, ln_g + l * 256,
                                                  ln_b + l * 256, hin_bf, hin_f32, h_bf, N);
    }
    unsigned short* feat_o = feat_bf;  // reuse; OSTR=64 rows fit in 256-wide buffer
    float* elo = el;
    float* ero = er;
    gemm_out_mfma<<<(N + 127) / 128, 256, 0, stream>>>(h_bf, Wt_o, al_o, ar_o, feat_o, elo, ero, N);
    aggregate_out<<<nb4, 256, 0, stream>>>(feat_o, elo, ero, start, endp, col, bias_o, out, N);
}